// Round 7
// baseline (480.692 us; speedup 1.0000x reference)
//
#include <hip/hip_runtime.h>
#include <hip/hip_bf16.h>

#define NN0 200000
#define NN1 50000
#define NN2 10000
#define IN_DIM 512
#define HD 256
#define OUT_D 128

typedef unsigned short u16;
typedef unsigned int u32;
typedef __attribute__((ext_vector_type(8))) short s16x8;
typedef __attribute__((ext_vector_type(4))) float f32x4;

__device__ __forceinline__ float b2f(u16 u){ return __uint_as_float(((u32)u)<<16); }
__device__ __forceinline__ u16 f2b(float f){
  u32 x = __float_as_uint(f);
  u32 r = x + 0x7fffu + ((x>>16)&1u);
  return (u16)(r>>16);
}

// direct global->LDS 16B async copy. LDS dest: wave-uniform base + lane*16.
__device__ __forceinline__ void gl_lds16(const void* g, void* l){
  __builtin_amdgcn_global_load_lds((const __attribute__((address_space(1))) u32*)g,
                                   (__attribute__((address_space(3))) u32*)l, 16, 0, 0);
}

// ---- fast zero fill (replaces pathologically slow runtime fillBuffer) ----
__global__ void zero_cnt(int4* __restrict__ p, int n16){
  int i = blockIdx.x*256 + threadIdx.x;
  if (i < n16) p[i] = make_int4(0,0,0,0);
}

// ---- fused degree counting for both graphs ----
__global__ void prep_deg(const int* __restrict__ s0, const int* __restrict__ d0, int E0,
                         const int* __restrict__ s1, const int* __restrict__ d1, int E1,
                         int* __restrict__ outc0, int* __restrict__ inc0,
                         int* __restrict__ outc1, int* __restrict__ inc1){
  int i = blockIdx.x*blockDim.x + threadIdx.x;
  if (i < E0){ atomicAdd(&outc0[s0[i]], 1); atomicAdd(&inc0[d0[i]], 1); }
  if (i < E1){ atomicAdd(&outc1[s1[i]], 1); atomicAdd(&inc1[d1[i]], 1); }
}

// ---- fused rsqrt-degree scales ----
__global__ void prep_scale(const int* __restrict__ outc0, float* __restrict__ so0,
                           const int* __restrict__ inc0,  float* __restrict__ ri0,
                           const int* __restrict__ outc1, float* __restrict__ so1,
                           const int* __restrict__ inc1,  float* __restrict__ ri1){
  int i = blockIdx.x*blockDim.x + threadIdx.x;
  if (i < NN0) so0[i] = rsqrtf((float)(outc0[i] > 1 ? outc0[i] : 1));
  if (i < NN1){
    ri0[i] = rsqrtf((float)(inc0[i]  > 1 ? inc0[i]  : 1));
    so1[i] = rsqrtf((float)(outc1[i] > 1 ? outc1[i] : 1));
  }
  if (i < NN2) ri1[i] = rsqrtf((float)(inc1[i] > 1 ? inc1[i] : 1));
}

// ---- exclusive scan (single block per graph, shuffle-based) ----
__device__ void scan_dev(const int* __restrict__ cnt, int* __restrict__ off,
                         int* __restrict__ cur, int n){
  __shared__ int wsum[16];
  int tid = threadIdx.x, lane = tid & 63, wv = tid >> 6;
  int carry = 0;
  for (int base = 0; base < n; base += 1024){
    int i = base + tid;
    int v = (i < n) ? cnt[i] : 0;
    int x = v;
    #pragma unroll
    for (int d = 1; d < 64; d <<= 1){
      int y = __shfl_up(x, d);
      if (lane >= d) x += y;
    }
    if (lane == 63) wsum[wv] = x;
    __syncthreads();
    if (tid == 0){
      int s = carry;
      #pragma unroll
      for (int k = 0; k < 16; ++k){ int t = wsum[k]; wsum[k] = s; s += t; }
      carry = s;
    }
    __syncthreads();
    int excl = wsum[wv] + x - v;
    if (i < n){ off[i] = excl; cur[i] = excl; }
    __syncthreads();
  }
  if (tid == 0) off[n] = carry;
}

__global__ __launch_bounds__(1024) void scan2_kernel(
    const int* c0, int* o0, int* u0, int n0,
    const int* c1, int* o1, int* u1, int n1){
  if (blockIdx.x == 0) scan_dev(c0, o0, u0, n0);
  else                 scan_dev(c1, o1, u1, n1);
}

// ---- fused CSR fill for both graphs ----
__global__ void fill2_kernel(const int* __restrict__ s0, const int* __restrict__ d0, int E0,
                             int* __restrict__ cur0, int* __restrict__ l0,
                             const int* __restrict__ s1, const int* __restrict__ d1, int E1,
                             int* __restrict__ cur1, int* __restrict__ l1){
  int i = blockIdx.x*blockDim.x + threadIdx.x;
  if (i < E0){ int d = d0[i]; l0[atomicAdd(&cur0[d], 1)] = s0[i]; }
  if (i < E1){ int d = d1[i]; l1[atomicAdd(&cur1[d], 1)] = s1[i]; }
}

// ---- pack W [K][N] f32 into MFMA-B fragment-linear bf16 ----
__device__ __forceinline__ void pack_one(const float* __restrict__ W, u16* __restrict__ out,
                                         int K, int N, int c){
  int lane = c & 63;
  int f = (c >> 6) % (N>>4);
  int s = (c >> 6) / (N>>4);
  int col = f*16 + (lane & 15);
  int k0 = s*32 + (lane >> 4)*8;
  u16* o = out + (size_t)c*8;
  #pragma unroll
  for (int e = 0; e < 8; ++e) o[e] = f2b(W[(size_t)(k0+e)*N + col]);
}

__global__ void wpack3(const float* W1, u16* P1, const float* Wc, u16* Pc,
                       const float* Wo, u16* Po){
  int c = blockIdx.x*256 + threadIdx.x;
  // totals: W1 (512x256)->16384, Wc (256x256)->8192, Wo (256x128)->4096
  if (c < 16384)      pack_one(W1, P1, IN_DIM, HD, c);
  else if (c < 24576) pack_one(Wc, Pc, HD, HD, c - 16384);
  else if (c < 28672) pack_one(Wo, Po, HD, OUT_D, c - 24576);
}

// ---- MFMA GEMM, global_load_lds A-staging, counted-vmcnt pipeline (T3/T4) ----
// C[M,N] = A[M,K] @ W[K,N] + bias. A: f32 (ABF=false) or bf16 row-major.
// BPK: fragment-packed bf16 (wpack), L2-resident. Tile 128x128, BK=64,
// A double-buffered via glds(16B), 16B-XOR swizzle (linear LDS dest,
// pre-swizzled global src, swizzled ds_read). Two raw barriers per tile,
// vmcnt never drained to 0 in-loop: stage(t+1) stays in flight.
template<int K, int N, bool ABF, bool RELU, bool OBF>
__global__ __launch_bounds__(256) void gemm_glds(const void* __restrict__ Av,
    const u16* __restrict__ BPK, const float* __restrict__ bias,
    void* __restrict__ Cv, int M)
{
  constexpr int ESZ   = ABF ? 2 : 4;
  constexpr int SLOTS = (64*ESZ)/16;       // 16B slots per 64-elem row: 8 / 16
  constexpr int SMSK  = SLOTS - 1;
  constexpr int ROWB  = 64*ESZ;
  constexpr int TILEB = 128*64*ESZ;        // 16 KB / 32 KB
  constexpr int IW    = TILEB/1024/4;      // glds per wave per stage: 4 / 8
  constexpr int NT    = K/64;
  constexpr int NF16  = N/16;
  constexpr int NYB   = N/128;
  constexpr int LDSB  = (2*TILEB > 34816) ? 2*TILEB : 34816;
  __shared__ char smem[LDSB];

  const int t = threadIdx.x;
  const int lane = t & 63;
  const int wv = t >> 6;
  const int wr = wv >> 1, wc = wv & 1;

  // XCD-bijective block swizzle (m204): contiguous logical chunks per XCD
  int b;
  {
    int nb = gridDim.x, h = blockIdx.x;
    if (nb >= 8){
      int q = nb >> 3, r = nb & 7, k = h & 7, pos = h >> 3;
      b = (k < r ? k*(q+1) : r*(q+1) + (k-r)*q) + pos;
    } else b = h;
  }
  const int by = b % NYB;
  const int r0 = (b / NYB) * 128;
  const int c0 = by * 128;
  const int m15 = lane & 15, kg = lane >> 4;

  auto stage = [&](int buf, int ti){
    const int k0 = ti*64;
    char* bb = smem + buf*TILEB;
    #pragma unroll
    for (int s = 0; s < IW; ++s){
      int i16 = (wv*IW + s)*64 + lane;
      int row = i16 / SLOTS;
      int tt  = i16 & SMSK;
      int tsrc = tt ^ (row & SMSK);
      int grc = min(r0 + row, M-1);
      const char* g = (const char*)Av + ((size_t)grc*K + k0)*ESZ + tsrc*16;
      gl_lds16(g, bb + (wv*IW + s)*1024);
    }
  };

  f32x4 acc[4][4] = {};

  stage(0, 0);

  for (int ti = 0; ti < NT; ++ti){
    // 1. B fragments (8 VMEM loads) — MUST precede stage for vmcnt accounting
    s16x8 bfr[2][4];
    #pragma unroll
    for (int kh = 0; kh < 2; ++kh)
      #pragma unroll
      for (int j = 0; j < 4; ++j)
        bfr[kh][j] = *(const s16x8*)(BPK +
          (((size_t)(2*ti+kh)*NF16 + by*8 + wc*4 + j)*64 + lane)*8);
    __builtin_amdgcn_sched_barrier(0);

    // 2. prefetch next tile (stays in flight across the barrier)
    if (ti + 1 < NT) stage((ti+1)&1, ti+1);
    __builtin_amdgcn_sched_barrier(0);

    // 3. wait for MY stage(ti) only (in-order vmcnt retire: all but newest N done)
    if (ti + 1 < NT){
      if constexpr (IW == 8) asm volatile("s_waitcnt vmcnt(16)");
      else                   asm volatile("s_waitcnt vmcnt(12)");
    } else {
      asm volatile("s_waitcnt vmcnt(8)");
    }
    __builtin_amdgcn_s_barrier();            // all waves' stage(ti) visible
    __builtin_amdgcn_sched_barrier(0);

    // 4. LDS -> A fragments (swizzled), cvt if f32
    const char* bb = smem + (ti&1)*TILEB;
    s16x8 afr[2][4];
    #pragma unroll
    for (int kh = 0; kh < 2; ++kh){
      #pragma unroll
      for (int i = 0; i < 4; ++i){
        int row_l = wr*64 + i*16 + m15;
        if (ABF){
          int s = kh*4 + kg;
          int sw = s ^ (row_l & SMSK);
          afr[kh][i] = *(const s16x8*)(bb + row_l*ROWB + sw*16);
        } else {
          int s0 = kh*8 + kg*2;
          int sw0 = s0 ^ (row_l & SMSK);
          int sw1 = (s0+1) ^ (row_l & SMSK);
          float4 lo = *(const float4*)(bb + row_l*ROWB + sw0*16);
          float4 hi = *(const float4*)(bb + row_l*ROWB + sw1*16);
          s16x8 v;
          v[0]=(short)f2b(lo.x); v[1]=(short)f2b(lo.y); v[2]=(short)f2b(lo.z); v[3]=(short)f2b(lo.w);
          v[4]=(short)f2b(hi.x); v[5]=(short)f2b(hi.y); v[6]=(short)f2b(hi.z); v[7]=(short)f2b(hi.w);
          afr[kh][i] = v;
        }
      }
    }

    // 5. MFMA (compiler inserts lgkmcnt for afr + vmcnt(IW) for bfr)
    #pragma unroll
    for (int kh = 0; kh < 2; ++kh)
      #pragma unroll
      for (int i = 0; i < 4; ++i)
        #pragma unroll
        for (int j = 0; j < 4; ++j)
          acc[i][j] = __builtin_amdgcn_mfma_f32_16x16x32_bf16(afr[kh][i], bfr[kh][j], acc[i][j], 0, 0, 0);

    // 6. read-protect: nobody overwrites buf(ti) (via stage(ti+2)) until all read it
    __builtin_amdgcn_sched_barrier(0);
    __builtin_amdgcn_s_barrier();
  }

  __syncthreads();   // full drain before LDS reuse in epilogue

  if (OBF){
    // repack epilogue: acc -> LDS u16 [128][136] -> coalesced 16B stores
    u16* cs = (u16*)smem;
    #pragma unroll
    for (int j = 0; j < 4; ++j){
      int colg = c0 + wc*64 + j*16 + m15;
      float bv = bias[colg];
      #pragma unroll
      for (int i = 0; i < 4; ++i){
        int rl = wr*64 + i*16 + kg*4;
        #pragma unroll
        for (int q = 0; q < 4; ++q){
          float v = acc[i][j][q] + bv;
          if (RELU) v = fmaxf(v, 0.f);
          cs[(rl+q)*136 + wc*64 + j*16 + m15] = f2b(v);
        }
      }
    }
    __syncthreads();
    int rr = t >> 1, hh = t & 1;
    int go = r0 + rr;
    if (go < M){
      u16* dst = (u16*)Cv + (size_t)go*N + c0 + hh*64;
      const u16* sp = &cs[rr*136 + hh*64];
      #pragma unroll
      for (int c = 0; c < 8; ++c) *(s16x8*)(dst + c*8) = *(const s16x8*)(sp + c*8);
    }
  } else {
    #pragma unroll
    for (int j = 0; j < 4; ++j){
      int colg = c0 + wc*64 + j*16 + m15;
      float bv = bias[colg];
      #pragma unroll
      for (int i = 0; i < 4; ++i){
        int rbase = r0 + wr*64 + i*16 + kg*4;
        #pragma unroll
        for (int q = 0; q < 4; ++q){
          int row = rbase + q;
          if (row < M){
            float v = acc[i][j][q] + bv;
            if (RELU) v = fmaxf(v, 0.f);
            ((float*)Cv)[(size_t)row*N + colg] = v;
          }
        }
      }
    }
  }
}

// ---- CSR pull aggregation, 4x-unrolled edge loop for memory-level parallelism ----
__global__ __launch_bounds__(256) void agg_kernel(const u16* __restrict__ X,
    const int* __restrict__ off, const int* __restrict__ lst,
    const float* __restrict__ so, const float* __restrict__ ri,
    u16* __restrict__ out, int nd)
{
  int lane = threadIdx.x & 63, wv = threadIdx.x >> 6;
  int d = blockIdx.x*4 + wv;
  if (d >= nd) return;
  int e0 = off[d], e1 = off[d+1];
  float a0=0.f, a1=0.f, a2=0.f, a3=0.f;
  int e = e0;
  for (; e + 4 <= e1; e += 4){
    int s0 = lst[e], s1 = lst[e+1], s2 = lst[e+2], s3 = lst[e+3];
    float c0 = so[s0], c1 = so[s1], c2 = so[s2], c3 = so[s3];
    ushort4 u0 = ((const ushort4*)X)[(size_t)s0*64 + lane];
    ushort4 u1 = ((const ushort4*)X)[(size_t)s1*64 + lane];
    ushort4 u2 = ((const ushort4*)X)[(size_t)s2*64 + lane];
    ushort4 u3 = ((const ushort4*)X)[(size_t)s3*64 + lane];
    a0 = fmaf(b2f(u0.x), c0, a0); a1 = fmaf(b2f(u0.y), c0, a1);
    a2 = fmaf(b2f(u0.z), c0, a2); a3 = fmaf(b2f(u0.w), c0, a3);
    a0 = fmaf(b2f(u1.x), c1, a0); a1 = fmaf(b2f(u1.y), c1, a1);
    a2 = fmaf(b2f(u1.z), c1, a2); a3 = fmaf(b2f(u1.w), c1, a3);
    a0 = fmaf(b2f(u2.x), c2, a0); a1 = fmaf(b2f(u2.y), c2, a1);
    a2 = fmaf(b2f(u2.z), c2, a2); a3 = fmaf(b2f(u2.w), c2, a3);
    a0 = fmaf(b2f(u3.x), c3, a0); a1 = fmaf(b2f(u3.y), c3, a1);
    a2 = fmaf(b2f(u3.z), c3, a2); a3 = fmaf(b2f(u3.w), c3, a3);
  }
  for (; e < e1; ++e){
    int s = lst[e];
    float sc = so[s];
    ushort4 u = ((const ushort4*)X)[(size_t)s*64 + lane];
    a0 = fmaf(b2f(u.x), sc, a0);
    a1 = fmaf(b2f(u.y), sc, a1);
    a2 = fmaf(b2f(u.z), sc, a2);
    a3 = fmaf(b2f(u.w), sc, a3);
  }
  float r = ri[d];
  ushort4 o;
  o.x = f2b(a0*r); o.y = f2b(a1*r); o.z = f2b(a2*r); o.w = f2b(a3*r);
  ((ushort4*)out)[(size_t)d*64 + lane] = o;
}

// ---- LayerNorm over 256 cols, in-place bf16, one wave per row ----
__global__ __launch_bounds__(256) void ln_kernel(u16* __restrict__ H,
    const float* __restrict__ g, const float* __restrict__ b, int n)
{
  int lane = threadIdx.x & 63, wv = threadIdx.x >> 6;
  int r = blockIdx.x*4 + wv;
  if (r >= n) return;
  ushort4 u = ((const ushort4*)H)[(size_t)r*64 + lane];
  float x0=b2f(u.x), x1=b2f(u.y), x2=b2f(u.z), x3=b2f(u.w);
  float s = x0+x1+x2+x3;
  #pragma unroll
  for (int d=1; d<64; d<<=1) s += __shfl_xor(s, d);
  float mu = s * (1.f/256.f);
  float d0=x0-mu, d1=x1-mu, d2=x2-mu, d3=x3-mu;
  float v = d0*d0 + d1*d1 + d2*d2 + d3*d3;
  #pragma unroll
  for (int d=1; d<64; d<<=1) v += __shfl_xor(v, d);
  float inv = rsqrtf(v*(1.f/256.f) + 1e-5f);
  float4 gv = ((const float4*)g)[lane];
  float4 bv = ((const float4*)b)[lane];
  ushort4 o;
  o.x = f2b(d0*inv*gv.x + bv.x);
  o.y = f2b(d1*inv*gv.y + bv.y);
  o.z = f2b(d2*inv*gv.z + bv.z);
  o.w = f2b(d3*inv*gv.w + bv.w);
  ((ushort4*)H)[(size_t)r*64 + lane] = o;
}

// ---- row L2-normalize, 128 cols, one wave per row ----
__global__ __launch_bounds__(256) void rownorm_kernel(const float* __restrict__ T,
    float* __restrict__ out, int n)
{
  int lane = threadIdx.x & 63, wv = threadIdx.x >> 6;
  int r = blockIdx.x*4 + wv;
  if (r >= n) return;
  float2 x = ((const float2*)T)[(size_t)r*64 + lane];
  float s = x.x*x.x + x.y*x.y;
  #pragma unroll
  for (int d=1; d<64; d<<=1) s += __shfl_xor(s, d);
  float nrm = sqrtf(s);
  float sc = 1.f / fmaxf(nrm, 1e-12f);
  float2 o; o.x = x.x*sc; o.y = x.y*sc;
  ((float2*)out)[(size_t)r*64 + lane] = o;
}

extern "C" void kernel_launch(void* const* d_in, const int* in_sizes, int n_in,
                              void* d_out, int out_size, void* d_ws, size_t ws_size,
                              hipStream_t stream)
{
  const float* feats = (const float*)d_in[0];
  const int*   b0s   = (const int*)d_in[1];
  const int*   b0d   = (const int*)d_in[2];
  const int*   b1s   = (const int*)d_in[3];
  const int*   b1d   = (const int*)d_in[4];
  const float* W1    = (const float*)d_in[5];
  const float* bias1 = (const float*)d_in[6];
  const float* Wc    = (const float*)d_in[7];
  const float* bc    = (const float*)d_in[8];
  const float* lng   = (const float*)d_in[9];
  const float* lnb   = (const float*)d_in[10];
  const float* Wo    = (const float*)d_in[11];
  const float* bo    = (const float*)d_in[12];
  const int E0 = in_sizes[1];
  const int E1 = in_sizes[3];
  (void)n_in; (void)out_size; (void)ws_size;

  char* p = (char*)d_ws;
  auto alloc = [&](size_t bytes)->void*{ void* q = (void*)p; p += (bytes + 255) & ~(size_t)255; return q; };
  u16*   g1   = (u16*)  alloc((size_t)NN0*HD*2);     // GEMM1 out; reused for conv1 out + LN
  u16*   hb   = (u16*)  alloc((size_t)NN1*HD*2);     // agg1 out
  u16*   ag2  = (u16*)  alloc((size_t)NN2*HD*2);
  float* c2   = (float*)alloc((size_t)NN2*OUT_D*4);
  u16*   W1P  = (u16*)  alloc((size_t)HD*IN_DIM*2);
  u16*   WcP  = (u16*)  alloc((size_t)HD*HD*2);
  u16*   WoP  = (u16*)  alloc((size_t)OUT_D*HD*2);
  char* cnt_begin = p;
  int* outc0 = (int*)alloc((size_t)NN0*4);
  int* inc0  = (int*)alloc((size_t)NN1*4);
  int* outc1 = (int*)alloc((size_t)NN1*4);
  int* inc1  = (int*)alloc((size_t)NN2*4);
  char* cnt_end = p;
  float* so0 = (float*)alloc((size_t)NN0*4);
  float* ri0 = (float*)alloc((size_t)NN1*4);
  float* so1 = (float*)alloc((size_t)NN1*4);
  float* ri1 = (float*)alloc((size_t)NN2*4);
  int* off0  = (int*)alloc((size_t)(NN1+1)*4);
  int* cur0  = (int*)alloc((size_t)NN1*4);
  int* off1  = (int*)alloc((size_t)(NN2+1)*4);
  int* cur1  = (int*)alloc((size_t)NN2*4);
  int* lst0  = (int*)alloc((size_t)800000*4);
  int* lst1  = (int*)alloc((size_t)160000*4);

  // zero the atomic-counter region with a proper grid (runtime fill kernel
  // for this region measured 246 us; this is <2 us)
  {
    int nbytes = (int)(cnt_end - cnt_begin);
    int n16 = nbytes >> 4;                       // region is 256B-aligned
    zero_cnt<<<(n16 + 255)/256, 256, 0, stream>>>((int4*)cnt_begin, n16);
  }

  // graph prep (fused: 5 launches)
  {
    int Emax = E0 > E1 ? E0 : E1;
    prep_deg<<<(Emax+255)/256, 256, 0, stream>>>(b0s, b0d, E0, b1s, b1d, E1,
                                                 outc0, inc0, outc1, inc1);
    prep_scale<<<(NN0+255)/256, 256, 0, stream>>>(outc0, so0, inc0, ri0, outc1, so1, inc1, ri1);
    scan2_kernel<<<2, 1024, 0, stream>>>(inc0, off0, cur0, NN1, inc1, off1, cur1, NN2);
    fill2_kernel<<<(Emax+255)/256, 256, 0, stream>>>(b0s, b0d, E0, cur0, lst0,
                                                     b1s, b1d, E1, cur1, lst1);
    wpack3<<<112, 256, 0, stream>>>(W1, W1P, Wc, WcP, Wo, WoP);
  }

  // h = feats @ W1 + bias1   [200000,512]@[512,256] -> g1 (bf16)
  {
    int nblk = ((NN0+127)/128) * (HD/128);
    gemm_glds<IN_DIM, HD, false, false, true><<<nblk, 256, 0, stream>>>(feats, W1P, bias1, g1, NN0);
  }
  // agg1 over b0 -> hb
  agg_kernel<<<(NN1+3)/4, 256, 0, stream>>>(g1, off0, lst0, so0, ri0, hb, NN1);
  // conv1 = relu(agg1 @ Wc + bc)  [50000,256]@[256,256] -> g1 (region reuse; hb intact)
  {
    int nblk = ((NN1+127)/128) * (HD/128);
    gemm_glds<HD, HD, true, true, true><<<nblk, 256, 0, stream>>>(hb, WcP, bc, g1, NN1);
  }
  // LayerNorm in-place on g1[0:NN1]
  ln_kernel<<<(NN1+3)/4, 256, 0, stream>>>(g1, lng, lnb, NN1);
  // agg2 over b1 -> ag2
  agg_kernel<<<(NN2+3)/4, 256, 0, stream>>>(g1, off1, lst1, so1, ri1, ag2, NN2);
  // conv2 = agg2 @ Wo + bo  [10000,256]@[256,128] -> c2 (f32)
  {
    int nblk = ((NN2+127)/128) * (OUT_D/128);
    gemm_glds<HD, OUT_D, true, false, false><<<nblk, 256, 0, stream>>>(ag2, WoP, bo, c2, NN2);
  }
  // row L2 normalize -> d_out (f32)
  rownorm_kernel<<<(NN2+3)/4, 256, 0, stream>>>(c2, (float*)d_out, NN2);
}

// Round 8
// 433.089 us; speedup vs baseline: 1.1099x; 1.1099x over previous
//
#include <hip/hip_runtime.h>
#include <hip/hip_bf16.h>

#define NN0 200000
#define NN1 50000
#define NN2 10000
#define IN_DIM 512
#define HD 256
#define OUT_D 128
#define CH0 ((NN1+1023)/1024)   // 49 scan chunks, graph0
#define CH1 ((NN2+1023)/1024)   // 10 scan chunks, graph1

typedef unsigned short u16;
typedef unsigned int u32;
typedef __attribute__((ext_vector_type(8))) short s16x8;
typedef __attribute__((ext_vector_type(4))) float f32x4;

__device__ __forceinline__ float b2f(u16 u){ return __uint_as_float(((u32)u)<<16); }
__device__ __forceinline__ u16 f2b(float f){
  u32 x = __float_as_uint(f);
  u32 r = x + 0x7fffu + ((x>>16)&1u);
  return (u16)(r>>16);
}

// direct global->LDS 16B async copy. LDS dest: wave-uniform base + lane*16.
__device__ __forceinline__ void gl_lds16(const void* g, void* l){
  __builtin_amdgcn_global_load_lds((const __attribute__((address_space(1))) u32*)g,
                                   (__attribute__((address_space(3))) u32*)l, 16, 0, 0);
}

// ---- fused: zero counter region (blocks < nzb) + pack weights (blocks >= nzb) ----
__device__ __forceinline__ void pack_one(const float* __restrict__ W, u16* __restrict__ out,
                                         int K, int N, int c){
  int lane = c & 63;
  int f = (c >> 6) % (N>>4);
  int s = (c >> 6) / (N>>4);
  int col = f*16 + (lane & 15);
  int k0 = s*32 + (lane >> 4)*8;
  u16* o = out + (size_t)c*8;
  #pragma unroll
  for (int e = 0; e < 8; ++e) o[e] = f2b(W[(size_t)(k0+e)*N + col]);
}

__global__ void wpz_kernel(int4* __restrict__ zp, int n16, int nzb,
                           const float* W1, u16* P1, const float* Wc, u16* Pc,
                           const float* Wo, u16* Po){
  int b = blockIdx.x;
  if (b < nzb){
    int i = b*256 + threadIdx.x;
    if (i < n16) zp[i] = make_int4(0,0,0,0);
  } else {
    int c = (b - nzb)*256 + threadIdx.x;
    if (c < 16384)      pack_one(W1, P1, IN_DIM, HD, c);
    else if (c < 24576) pack_one(Wc, Pc, HD, HD, c - 16384);
    else if (c < 28672) pack_one(Wo, Po, HD, OUT_D, c - 24576);
  }
}

// ---- fused degree counting for both graphs ----
__global__ void prep_deg(const int* __restrict__ s0, const int* __restrict__ d0, int E0,
                         const int* __restrict__ s1, const int* __restrict__ d1, int E1,
                         int* __restrict__ outc0, int* __restrict__ inc0,
                         int* __restrict__ outc1, int* __restrict__ inc1){
  int i = blockIdx.x*blockDim.x + threadIdx.x;
  if (i < E0){ atomicAdd(&outc0[s0[i]], 1); atomicAdd(&inc0[d0[i]], 1); }
  if (i < E1){ atomicAdd(&outc1[s1[i]], 1); atomicAdd(&inc1[d1[i]], 1); }
}

// ---- fused rsqrt-degree scales ----
__global__ void prep_scale(const int* __restrict__ outc0, float* __restrict__ so0,
                           const int* __restrict__ inc0,  float* __restrict__ ri0,
                           const int* __restrict__ outc1, float* __restrict__ so1,
                           const int* __restrict__ inc1,  float* __restrict__ ri1){
  int i = blockIdx.x*blockDim.x + threadIdx.x;
  if (i < NN0) so0[i] = rsqrtf((float)(outc0[i] > 1 ? outc0[i] : 1));
  if (i < NN1){
    ri0[i] = rsqrtf((float)(inc0[i]  > 1 ? inc0[i]  : 1));
    so1[i] = rsqrtf((float)(outc1[i] > 1 ? outc1[i] : 1));
  }
  if (i < NN2) ri1[i] = rsqrtf((float)(inc1[i] > 1 ? inc1[i] : 1));
}

// ---- two-level exclusive scan: partials -> chunk-sum scan -> add-back ----
// k1: per-chunk exclusive scan (partial, no chunk base) + chunk total
__global__ __launch_bounds__(1024) void scan_part(const int* __restrict__ c0, int* __restrict__ o0,
                                                  const int* __restrict__ c1, int* __restrict__ o1,
                                                  int* __restrict__ bsum){
  __shared__ int wsum[16];
  int b = blockIdx.x;
  const int* cnt; int* off; int n, base, slot;
  if (b < CH0){ cnt = c0; off = o0; n = NN1; base = b*1024; slot = b; }
  else        { int bb = b - CH0; cnt = c1; off = o1; n = NN2; base = bb*1024; slot = CH0 + bb; }
  int tid = threadIdx.x, lane = tid & 63, wv = tid >> 6;
  int i = base + tid;
  int v = (i < n) ? cnt[i] : 0;
  int x = v;
  #pragma unroll
  for (int d = 1; d < 64; d <<= 1){
    int y = __shfl_up(x, d);
    if (lane >= d) x += y;
  }
  if (lane == 63) wsum[wv] = x;
  __syncthreads();
  if (wv == 0){
    int s = (lane < 16) ? wsum[lane] : 0;
    #pragma unroll
    for (int d = 1; d < 16; d <<= 1){
      int y = __shfl_up(s, d);
      if (lane >= d) s += y;
    }
    if (lane < 16) wsum[lane] = s;            // inclusive wave-sums
  }
  __syncthreads();
  int wbase = wv ? wsum[wv-1] : 0;
  if (i < n) off[i] = wbase + x - v;          // exclusive within chunk
  if (tid == 0) bsum[slot] = wsum[15];        // chunk total
}

// k2: wave-scan the chunk sums (49 and 10 entries), write totals to off[n]
__global__ __launch_bounds__(128) void scan_bsum(const int* __restrict__ bsum,
                                                 int* __restrict__ cbase,
                                                 int* __restrict__ o0, int* __restrict__ o1){
  int lane = threadIdx.x & 63;
  int w = threadIdx.x >> 6;
  if (w == 0){
    int v = (lane < CH0) ? bsum[lane] : 0;
    int x = v;
    #pragma unroll
    for (int d = 1; d < 64; d <<= 1){ int y = __shfl_up(x, d); if (lane >= d) x += y; }
    if (lane < CH0) cbase[lane] = x - v;
    if (lane == CH0-1) o0[NN1] = x;
  } else {
    int v = (lane < CH1) ? bsum[CH0 + lane] : 0;
    int x = v;
    #pragma unroll
    for (int d = 1; d < 64; d <<= 1){ int y = __shfl_up(x, d); if (lane >= d) x += y; }
    if (lane < CH1) cbase[CH0 + lane] = x - v;
    if (lane == CH1-1) o1[NN2] = x;
  }
}

// k3: add chunk bases, emit final off + cur copy
__global__ __launch_bounds__(1024) void scan_add(int* __restrict__ o0, int* __restrict__ u0,
                                                 int* __restrict__ o1, int* __restrict__ u1,
                                                 const int* __restrict__ cbase){
  int b = blockIdx.x;
  int* off; int* cur; int n, base, slot;
  if (b < CH0){ off = o0; cur = u0; n = NN1; base = b*1024; slot = b; }
  else        { int bb = b - CH0; off = o1; cur = u1; n = NN2; base = bb*1024; slot = CH0 + bb; }
  int i = base + threadIdx.x;
  if (i < n){
    int t = off[i] + cbase[slot];
    off[i] = t; cur[i] = t;
  }
}

// ---- fused CSR fill for both graphs; stores (src, out-scale) pairs ----
__global__ void fill2_kernel(const int* __restrict__ s0, const int* __restrict__ d0, int E0,
                             int* __restrict__ cur0, int2* __restrict__ l0, const float* __restrict__ so0,
                             const int* __restrict__ s1, const int* __restrict__ d1, int E1,
                             int* __restrict__ cur1, int2* __restrict__ l1, const float* __restrict__ so1){
  int i = blockIdx.x*blockDim.x + threadIdx.x;
  if (i < E0){
    int s = s0[i];
    int p = atomicAdd(&cur0[d0[i]], 1);
    l0[p] = make_int2(s, __float_as_int(so0[s]));
  }
  if (i < E1){
    int s = s1[i];
    int p = atomicAdd(&cur1[d1[i]], 1);
    l1[p] = make_int2(s, __float_as_int(so1[s]));
  }
}

// ---- MFMA GEMM, global_load_lds A-staging, counted-vmcnt pipeline (T3/T4) ----
template<int K, int N, bool ABF, bool RELU, bool OBF>
__global__ __launch_bounds__(256) void gemm_glds(const void* __restrict__ Av,
    const u16* __restrict__ BPK, const float* __restrict__ bias,
    void* __restrict__ Cv, int M)
{
  constexpr int ESZ   = ABF ? 2 : 4;
  constexpr int SLOTS = (64*ESZ)/16;
  constexpr int SMSK  = SLOTS - 1;
  constexpr int ROWB  = 64*ESZ;
  constexpr int TILEB = 128*64*ESZ;
  constexpr int IW    = TILEB/1024/4;
  constexpr int NT    = K/64;
  constexpr int NF16  = N/16;
  constexpr int NYB   = N/128;
  constexpr int LDSB  = (2*TILEB > 34816) ? 2*TILEB : 34816;
  __shared__ char smem[LDSB];

  const int t = threadIdx.x;
  const int lane = t & 63;
  const int wv = t >> 6;
  const int wr = wv >> 1, wc = wv & 1;

  int b;
  {
    int nb = gridDim.x, h = blockIdx.x;
    if (nb >= 8){
      int q = nb >> 3, r = nb & 7, k = h & 7, pos = h >> 3;
      b = (k < r ? k*(q+1) : r*(q+1) + (k-r)*q) + pos;
    } else b = h;
  }
  const int by = b % NYB;
  const int r0 = (b / NYB) * 128;
  const int c0 = by * 128;
  const int m15 = lane & 15, kg = lane >> 4;

  auto stage = [&](int buf, int ti){
    const int k0 = ti*64;
    char* bb = smem + buf*TILEB;
    #pragma unroll
    for (int s = 0; s < IW; ++s){
      int i16 = (wv*IW + s)*64 + lane;
      int row = i16 / SLOTS;
      int tt  = i16 & SMSK;
      int tsrc = tt ^ (row & SMSK);
      int grc = min(r0 + row, M-1);
      const char* g = (const char*)Av + ((size_t)grc*K + k0)*ESZ + tsrc*16;
      gl_lds16(g, bb + (wv*IW + s)*1024);
    }
  };

  f32x4 acc[4][4] = {};

  stage(0, 0);

  for (int ti = 0; ti < NT; ++ti){
    s16x8 bfr[2][4];
    #pragma unroll
    for (int kh = 0; kh < 2; ++kh)
      #pragma unroll
      for (int j = 0; j < 4; ++j)
        bfr[kh][j] = *(const s16x8*)(BPK +
          (((size_t)(2*ti+kh)*NF16 + by*8 + wc*4 + j)*64 + lane)*8);
    __builtin_amdgcn_sched_barrier(0);

    if (ti + 1 < NT) stage((ti+1)&1, ti+1);
    __builtin_amdgcn_sched_barrier(0);

    if (ti + 1 < NT){
      if constexpr (IW == 8) asm volatile("s_waitcnt vmcnt(16)");
      else                   asm volatile("s_waitcnt vmcnt(12)");
    } else {
      asm volatile("s_waitcnt vmcnt(8)");
    }
    __builtin_amdgcn_s_barrier();
    __builtin_amdgcn_sched_barrier(0);

    const char* bb = smem + (ti&1)*TILEB;
    s16x8 afr[2][4];
    #pragma unroll
    for (int kh = 0; kh < 2; ++kh){
      #pragma unroll
      for (int i = 0; i < 4; ++i){
        int row_l = wr*64 + i*16 + m15;
        if (ABF){
          int s = kh*4 + kg;
          int sw = s ^ (row_l & SMSK);
          afr[kh][i] = *(const s16x8*)(bb + row_l*ROWB + sw*16);
        } else {
          int s0 = kh*8 + kg*2;
          int sw0 = s0 ^ (row_l & SMSK);
          int sw1 = (s0+1) ^ (row_l & SMSK);
          float4 lo = *(const float4*)(bb + row_l*ROWB + sw0*16);
          float4 hi = *(const float4*)(bb + row_l*ROWB + sw1*16);
          s16x8 v;
          v[0]=(short)f2b(lo.x); v[1]=(short)f2b(lo.y); v[2]=(short)f2b(lo.z); v[3]=(short)f2b(lo.w);
          v[4]=(short)f2b(hi.x); v[5]=(short)f2b(hi.y); v[6]=(short)f2b(hi.z); v[7]=(short)f2b(hi.w);
          afr[kh][i] = v;
        }
      }
    }

    #pragma unroll
    for (int kh = 0; kh < 2; ++kh)
      #pragma unroll
      for (int i = 0; i < 4; ++i)
        #pragma unroll
        for (int j = 0; j < 4; ++j)
          acc[i][j] = __builtin_amdgcn_mfma_f32_16x16x32_bf16(afr[kh][i], bfr[kh][j], acc[i][j], 0, 0, 0);

    __builtin_amdgcn_sched_barrier(0);
    __builtin_amdgcn_s_barrier();
  }

  __syncthreads();

  if (OBF){
    u16* cs = (u16*)smem;
    #pragma unroll
    for (int j = 0; j < 4; ++j){
      int colg = c0 + wc*64 + j*16 + m15;
      float bv = bias[colg];
      #pragma unroll
      for (int i = 0; i < 4; ++i){
        int rl = wr*64 + i*16 + kg*4;
        #pragma unroll
        for (int q = 0; q < 4; ++q){
          float v = acc[i][j][q] + bv;
          if (RELU) v = fmaxf(v, 0.f);
          cs[(rl+q)*136 + wc*64 + j*16 + m15] = f2b(v);
        }
      }
    }
    __syncthreads();
    int rr = t >> 1, hh = t & 1;
    int go = r0 + rr;
    if (go < M){
      u16* dst = (u16*)Cv + (size_t)go*N + c0 + hh*64;
      const u16* sp = &cs[rr*136 + hh*64];
      #pragma unroll
      for (int c = 0; c < 8; ++c) *(s16x8*)(dst + c*8) = *(const s16x8*)(sp + c*8);
    }
  } else {
    #pragma unroll
    for (int j = 0; j < 4; ++j){
      int colg = c0 + wc*64 + j*16 + m15;
      float bv = bias[colg];
      #pragma unroll
      for (int i = 0; i < 4; ++i){
        int rbase = r0 + wr*64 + i*16 + kg*4;
        #pragma unroll
        for (int q = 0; q < 4; ++q){
          int row = rbase + q;
          if (row < M){
            float v = acc[i][j][q] + bv;
            if (RELU) v = fmaxf(v, 0.f);
            ((float*)Cv)[(size_t)row*N + colg] = v;
          }
        }
      }
    }
  }
}

// ---- CSR pull aggregation: (src,scale) pairs, 4x-unrolled for MLP ----
__global__ __launch_bounds__(256) void agg_kernel(const u16* __restrict__ X,
    const int* __restrict__ off, const int2* __restrict__ lst,
    const float* __restrict__ ri, u16* __restrict__ out, int nd)
{
  int lane = threadIdx.x & 63, wv = threadIdx.x >> 6;
  int d = blockIdx.x*4 + wv;
  if (d >= nd) return;
  int e0 = off[d], e1 = off[d+1];
  float a0=0.f, a1=0.f, a2=0.f, a3=0.f;
  int e = e0;
  for (; e + 4 <= e1; e += 4){
    int2 p0 = lst[e], p1 = lst[e+1], p2 = lst[e+2], p3 = lst[e+3];
    float c0 = __int_as_float(p0.y), c1 = __int_as_float(p1.y);
    float c2 = __int_as_float(p2.y), c3 = __int_as_float(p3.y);
    ushort4 u0 = ((const ushort4*)X)[(size_t)p0.x*64 + lane];
    ushort4 u1 = ((const ushort4*)X)[(size_t)p1.x*64 + lane];
    ushort4 u2 = ((const ushort4*)X)[(size_t)p2.x*64 + lane];
    ushort4 u3 = ((const ushort4*)X)[(size_t)p3.x*64 + lane];
    a0 = fmaf(b2f(u0.x), c0, a0); a1 = fmaf(b2f(u0.y), c0, a1);
    a2 = fmaf(b2f(u0.z), c0, a2); a3 = fmaf(b2f(u0.w), c0, a3);
    a0 = fmaf(b2f(u1.x), c1, a0); a1 = fmaf(b2f(u1.y), c1, a1);
    a2 = fmaf(b2f(u1.z), c1, a2); a3 = fmaf(b2f(u1.w), c1, a3);
    a0 = fmaf(b2f(u2.x), c2, a0); a1 = fmaf(b2f(u2.y), c2, a1);
    a2 = fmaf(b2f(u2.z), c2, a2); a3 = fmaf(b2f(u2.w), c2, a3);
    a0 = fmaf(b2f(u3.x), c3, a0); a1 = fmaf(b2f(u3.y), c3, a1);
    a2 = fmaf(b2f(u3.z), c3, a2); a3 = fmaf(b2f(u3.w), c3, a3);
  }
  for (; e < e1; ++e){
    int2 pp = lst[e];
    float sc = __int_as_float(pp.y);
    ushort4 u = ((const ushort4*)X)[(size_t)pp.x*64 + lane];
    a0 = fmaf(b2f(u.x), sc, a0);
    a1 = fmaf(b2f(u.y), sc, a1);
    a2 = fmaf(b2f(u.z), sc, a2);
    a3 = fmaf(b2f(u.w), sc, a3);
  }
  float r = ri[d];
  ushort4 o;
  o.x = f2b(a0*r); o.y = f2b(a1*r); o.z = f2b(a2*r); o.w = f2b(a3*r);
  ((ushort4*)out)[(size_t)d*64 + lane] = o;
}

// ---- LayerNorm over 256 cols, in-place bf16, one wave per row ----
__global__ __launch_bounds__(256) void ln_kernel(u16* __restrict__ H,
    const float* __restrict__ g, const float* __restrict__ b, int n)
{
  int lane = threadIdx.x & 63, wv = threadIdx.x >> 6;
  int r = blockIdx.x*4 + wv;
  if (r >= n) return;
  ushort4 u = ((const ushort4*)H)[(size_t)r*64 + lane];
  float x0=b2f(u.x), x1=b2f(u.y), x2=b2f(u.z), x3=b2f(u.w);
  float s = x0+x1+x2+x3;
  #pragma unroll
  for (int d=1; d<64; d<<=1) s += __shfl_xor(s, d);
  float mu = s * (1.f/256.f);
  float d0=x0-mu, d1=x1-mu, d2=x2-mu, d3=x3-mu;
  float v = d0*d0 + d1*d1 + d2*d2 + d3*d3;
  #pragma unroll
  for (int d=1; d<64; d<<=1) v += __shfl_xor(v, d);
  float inv = rsqrtf(v*(1.f/256.f) + 1e-5f);
  float4 gv = ((const float4*)g)[lane];
  float4 bv = ((const float4*)b)[lane];
  ushort4 o;
  o.x = f2b(d0*inv*gv.x + bv.x);
  o.y = f2b(d1*inv*gv.y + bv.y);
  o.z = f2b(d2*inv*gv.z + bv.z);
  o.w = f2b(d3*inv*gv.w + bv.w);
  ((ushort4*)H)[(size_t)r*64 + lane] = o;
}

// ---- row L2-normalize, 128 cols, one wave per row ----
__global__ __launch_bounds__(256) void rownorm_kernel(const float* __restrict__ T,
    float* __restrict__ out, int n)
{
  int lane = threadIdx.x & 63, wv = threadIdx.x >> 6;
  int r = blockIdx.x*4 + wv;
  if (r >= n) return;
  float2 x = ((const float2*)T)[(size_t)r*64 + lane];
  float s = x.x*x.x + x.y*x.y;
  #pragma unroll
  for (int d=1; d<64; d<<=1) s += __shfl_xor(s, d);
  float nrm = sqrtf(s);
  float sc = 1.f / fmaxf(nrm, 1e-12f);
  float2 o; o.x = x.x*sc; o.y = x.y*sc;
  ((float2*)out)[(size_t)r*64 + lane] = o;
}

extern "C" void kernel_launch(void* const* d_in, const int* in_sizes, int n_in,
                              void* d_out, int out_size, void* d_ws, size_t ws_size,
                              hipStream_t stream)
{
  const float* feats = (const float*)d_in[0];
  const int*   b0s   = (const int*)d_in[1];
  const int*   b0d   = (const int*)d_in[2];
  const int*   b1s   = (const int*)d_in[3];
  const int*   b1d   = (const int*)d_in[4];
  const float* W1    = (const float*)d_in[5];
  const float* bias1 = (const float*)d_in[6];
  const float* Wc    = (const float*)d_in[7];
  const float* bc    = (const float*)d_in[8];
  const float* lng   = (const float*)d_in[9];
  const float* lnb   = (const float*)d_in[10];
  const float* Wo    = (const float*)d_in[11];
  const float* bo    = (const float*)d_in[12];
  const int E0 = in_sizes[1];
  const int E1 = in_sizes[3];
  (void)n_in; (void)out_size; (void)ws_size;

  char* p = (char*)d_ws;
  auto alloc = [&](size_t bytes)->void*{ void* q = (void*)p; p += (bytes + 255) & ~(size_t)255; return q; };
  u16*   g1   = (u16*)  alloc((size_t)NN0*HD*2);     // GEMM1 out; reused for conv1 out + LN
  u16*   hb   = (u16*)  alloc((size_t)NN1*HD*2);     // agg1 out
  u16*   ag2  = (u16*)  alloc((size_t)NN2*HD*2);
  float* c2   = (float*)alloc((size_t)NN2*OUT_D*4);
  u16*   W1P  = (u16*)  alloc((size_t)HD*IN_DIM*2);
  u16*   WcP  = (u16*)  alloc((size_t)HD*HD*2);
  u16*   WoP  = (u16*)  alloc((size_t)OUT_D*HD*2);
  char* cnt_begin = p;
  int* outc0 = (int*)alloc((size_t)NN0*4);
  int* inc0  = (int*)alloc((size_t)NN1*4);
  int* outc1 = (int*)alloc((size_t)NN1*4);
  int* inc1  = (int*)alloc((size_t)NN2*4);
  char* cnt_end = p;
  float* so0 = (float*)alloc((size_t)NN0*4);
  float* ri0 = (float*)alloc((size_t)NN1*4);
  float* so1 = (float*)alloc((size_t)NN1*4);
  float* ri1 = (float*)alloc((size_t)NN2*4);
  int* off0  = (int*)alloc((size_t)(NN1+1)*4);
  int* cur0  = (int*)alloc((size_t)NN1*4);
  int* off1  = (int*)alloc((size_t)(NN2+1)*4);
  int* cur1  = (int*)alloc((size_t)NN2*4);
  int2* lst0 = (int2*)alloc((size_t)800000*8);
  int2* lst1 = (int2*)alloc((size_t)160000*8);
  int* bsum  = (int*)alloc((size_t)(CH0+CH1)*4);
  int* cbase = (int*)alloc((size_t)(CH0+CH1)*4);

  // fused zero(counters) + weight-pack
  {
    int nbytes = (int)(cnt_end - cnt_begin);
    int n16 = nbytes >> 4;
    int nzb = (n16 + 255)/256;
    wpz_kernel<<<nzb + 112, 256, 0, stream>>>((int4*)cnt_begin, n16, nzb,
                                              W1, W1P, Wc, WcP, Wo, WoP);
  }

  // graph prep
  {
    int Emax = E0 > E1 ? E0 : E1;
    prep_deg<<<(Emax+255)/256, 256, 0, stream>>>(b0s, b0d, E0, b1s, b1d, E1,
                                                 outc0, inc0, outc1, inc1);
    prep_scale<<<(NN0+255)/256, 256, 0, stream>>>(outc0, so0, inc0, ri0, outc1, so1, inc1, ri1);
    scan_part<<<CH0+CH1, 1024, 0, stream>>>(inc0, off0, inc1, off1, bsum);
    scan_bsum<<<1, 128, 0, stream>>>(bsum, cbase, off0, off1);
    scan_add<<<CH0+CH1, 1024, 0, stream>>>(off0, cur0, off1, cur1, cbase);
    fill2_kernel<<<(Emax+255)/256, 256, 0, stream>>>(b0s, b0d, E0, cur0, lst0, so0,
                                                     b1s, b1d, E1, cur1, lst1, so1);
  }

  // h = feats @ W1 + bias1   [200000,512]@[512,256] -> g1 (bf16)
  {
    int nblk = ((NN0+127)/128) * (HD/128);
    gemm_glds<IN_DIM, HD, false, false, true><<<nblk, 256, 0, stream>>>(feats, W1P, bias1, g1, NN0);
  }
  // agg1 over b0 -> hb
  agg_kernel<<<(NN1+3)/4, 256, 0, stream>>>(g1, off0, lst0, ri0, hb, NN1);
  // conv1 = relu(agg1 @ Wc + bc)  [50000,256]@[256,256] -> g1 (region reuse; hb intact)
  {
    int nblk = ((NN1+127)/128) * (HD/128);
    gemm_glds<HD, HD, true, true, true><<<nblk, 256, 0, stream>>>(hb, WcP, bc, g1, NN1);
  }
  // LayerNorm in-place on g1[0:NN1]
  ln_kernel<<<(NN1+3)/4, 256, 0, stream>>>(g1, lng, lnb, NN1);
  // agg2 over b1 -> ag2
  agg_kernel<<<(NN2+3)/4, 256, 0, stream>>>(g1, off1, lst1, ri1, ag2, NN2);
  // conv2 = agg2 @ Wo + bo  [10000,256]@[256,128] -> c2 (f32)
  {
    int nblk = ((NN2+127)/128) * (OUT_D/128);
    gemm_glds<HD, OUT_D, true, false, false><<<nblk, 256, 0, stream>>>(ag2, WoP, bo, c2, NN2);
  }
  // row L2 normalize -> d_out (f32)
  rownorm_kernel<<<(NN2+3)/4, 256, 0, stream>>>(c2, (float*)d_out, NN2);
}

// Round 9
// 413.391 us; speedup vs baseline: 1.1628x; 1.0477x over previous
//
#include <hip/hip_runtime.h>
#include <hip/hip_bf16.h>

#define NN0 200000
#define NN1 50000
#define NN2 10000
#define IN_DIM 512
#define HD 256
#define OUT_D 128
#define CH0 ((NN1+1023)/1024)   // 49 scan chunks, graph0
#define CH1 ((NN2+1023)/1024)   // 10 scan chunks, graph1

typedef unsigned short u16;
typedef unsigned int u32;
typedef __attribute__((ext_vector_type(8))) short s16x8;
typedef __attribute__((ext_vector_type(4))) float f32x4;

__device__ __forceinline__ float b2f(u16 u){ return __uint_as_float(((u32)u)<<16); }
__device__ __forceinline__ u16 f2b(float f){
  u32 x = __float_as_uint(f);
  u32 r = x + 0x7fffu + ((x>>16)&1u);
  return (u16)(r>>16);
}

__device__ __forceinline__ void gl_lds16(const void* g, void* l){
  __builtin_amdgcn_global_load_lds((const __attribute__((address_space(1))) u32*)g,
                                   (__attribute__((address_space(3))) u32*)l, 16, 0, 0);
}

// ---- fused: zero counter region + pack weights ----
__device__ __forceinline__ void pack_one(const float* __restrict__ W, u16* __restrict__ out,
                                         int K, int N, int c){
  int lane = c & 63;
  int f = (c >> 6) % (N>>4);
  int s = (c >> 6) / (N>>4);
  int col = f*16 + (lane & 15);
  int k0 = s*32 + (lane >> 4)*8;
  u16* o = out + (size_t)c*8;
  #pragma unroll
  for (int e = 0; e < 8; ++e) o[e] = f2b(W[(size_t)(k0+e)*N + col]);
}

__global__ void wpz_kernel(int4* __restrict__ zp, int n16, int nzb,
                           const float* W1, u16* P1, const float* Wc, u16* Pc,
                           const float* Wo, u16* Po){
  int b = blockIdx.x;
  if (b < nzb){
    int i = b*256 + threadIdx.x;
    if (i < n16) zp[i] = make_int4(0,0,0,0);
  } else {
    int c = (b - nzb)*256 + threadIdx.x;
    if (c < 16384)      pack_one(W1, P1, IN_DIM, HD, c);
    else if (c < 24576) pack_one(Wc, Pc, HD, HD, c - 16384);
    else if (c < 28672) pack_one(Wo, Po, HD, OUT_D, c - 24576);
  }
}

// ---- fused scan_part (blocks < CH0+CH1) + rsqrt scales (rest) ----
__global__ __launch_bounds__(1024) void scan_scale(
    const int* __restrict__ c0, int* __restrict__ o0,
    const int* __restrict__ c1, int* __restrict__ o1, int* __restrict__ bsum,
    const int* __restrict__ outc0, float* __restrict__ so0,
    const int* __restrict__ inc0,  float* __restrict__ ri0,
    const int* __restrict__ outc1, float* __restrict__ so1,
    const int* __restrict__ inc1,  float* __restrict__ ri1)
{
  int b = blockIdx.x;
  if (b >= CH0+CH1){
    int i = (b - CH0 - CH1)*1024 + threadIdx.x;
    if (i < NN0) so0[i] = rsqrtf((float)(outc0[i] > 1 ? outc0[i] : 1));
    if (i < NN1){
      ri0[i] = rsqrtf((float)(inc0[i]  > 1 ? inc0[i]  : 1));
      so1[i] = rsqrtf((float)(outc1[i] > 1 ? outc1[i] : 1));
    }
    if (i < NN2) ri1[i] = rsqrtf((float)(inc1[i] > 1 ? inc1[i] : 1));
    return;
  }
  __shared__ int wsum[16];
  const int* cnt; int* off; int n, base, slot;
  if (b < CH0){ cnt = c0; off = o0; n = NN1; base = b*1024; slot = b; }
  else        { int bb = b - CH0; cnt = c1; off = o1; n = NN2; base = bb*1024; slot = CH0 + bb; }
  int tid = threadIdx.x, lane = tid & 63, wv = tid >> 6;
  int i = base + tid;
  int v = (i < n) ? cnt[i] : 0;
  int x = v;
  #pragma unroll
  for (int d = 1; d < 64; d <<= 1){
    int y = __shfl_up(x, d);
    if (lane >= d) x += y;
  }
  if (lane == 63) wsum[wv] = x;
  __syncthreads();
  if (wv == 0){
    int s = (lane < 16) ? wsum[lane] : 0;
    #pragma unroll
    for (int d = 1; d < 16; d <<= 1){
      int y = __shfl_up(s, d);
      if (lane >= d) s += y;
    }
    if (lane < 16) wsum[lane] = s;
  }
  __syncthreads();
  int wbase = wv ? wsum[wv-1] : 0;
  if (i < n) off[i] = wbase + x - v;
  if (tid == 0) bsum[slot] = wsum[15];
}

// ---- scan_add with inlined chunk-base scan (no separate scan_bsum launch) ----
__global__ __launch_bounds__(1024) void scan_add(int* __restrict__ o0, int* __restrict__ u0,
                                                 int* __restrict__ o1, int* __restrict__ u1,
                                                 const int* __restrict__ bsum){
  __shared__ int cbs;
  int b = blockIdx.x;
  int tid = threadIdx.x, lane = tid & 63, wv = tid >> 6;
  if (wv == 0){
    // graph0 chunk scan
    int v0 = (lane < CH0) ? bsum[lane] : 0;
    int x0 = v0;
    #pragma unroll
    for (int d = 1; d < 64; d <<= 1){ int y = __shfl_up(x0, d); if (lane >= d) x0 += y; }
    // graph1 chunk scan
    int v1 = (lane < CH1) ? bsum[CH0 + lane] : 0;
    int x1 = v1;
    #pragma unroll
    for (int d = 1; d < 64; d <<= 1){ int y = __shfl_up(x1, d); if (lane >= d) x1 += y; }
    int base = (b < CH0) ? __shfl(x0 - v0, b) : __shfl(x1 - v1, b - CH0);
    if (lane == 0) cbs = base;
    if (b == 0){
      if (lane == CH0-1) o0[NN1] = x0;
      if (lane == CH1-1) o1[NN2] = x1;
    }
  }
  __syncthreads();
  int base = cbs;
  int* off; int* cur; int n, i0;
  if (b < CH0){ off = o0; cur = u0; n = NN1; i0 = b*1024; }
  else        { off = o1; cur = u1; n = NN2; i0 = (b-CH0)*1024; }
  int i = i0 + tid;
  if (i < n){
    int t = off[i] + base;
    off[i] = t; cur[i] = t;
  }
}

// ---- fused CSR fill (src, out-scale) ----
__global__ void fill2_kernel(const int* __restrict__ s0, const int* __restrict__ d0, int E0,
                             int* __restrict__ cur0, int2* __restrict__ l0, const float* __restrict__ so0,
                             const int* __restrict__ s1, const int* __restrict__ d1, int E1,
                             int* __restrict__ cur1, int2* __restrict__ l1, const float* __restrict__ so1){
  int i = blockIdx.x*blockDim.x + threadIdx.x;
  if (i < E0){
    int s = s0[i];
    int p = atomicAdd(&cur0[d0[i]], 1);
    l0[p] = make_int2(s, __float_as_int(so0[s]));
  }
  if (i < E1){
    int s = s1[i];
    int p = atomicAdd(&cur1[d1[i]], 1);
    l1[p] = make_int2(s, __float_as_int(so1[s]));
  }
}

// ---- MFMA GEMM, glds staging, counted-vmcnt pipeline; optional fused deg / fused LN ----
// TH threads (256: 4 waves 2x2; 512: 8 waves 2x4); per-wave output always 64x64.
template<int K, int N, int BN, int TH, bool ABF, bool RELU, bool OBF, bool LNEP>
__global__ __launch_bounds__(TH) void gemm_glds(const void* __restrict__ Av,
    const u16* __restrict__ BPK, const float* __restrict__ bias,
    void* __restrict__ Cv, int M,
    const float* __restrict__ lng, const float* __restrict__ lnb,
    const int* __restrict__ gs0, const int* __restrict__ gd0, int dE0,
    const int* __restrict__ gs1, const int* __restrict__ gd1, int dE1,
    int* __restrict__ doc0, int* __restrict__ dic0,
    int* __restrict__ doc1, int* __restrict__ dic1, int degBlocks)
{
  constexpr int ESZ   = ABF ? 2 : 4;
  constexpr int SLOTS = (64*ESZ)/16;
  constexpr int SMSK  = SLOTS - 1;
  constexpr int ROWB  = 64*ESZ;
  constexpr int TILEB = 128*64*ESZ;
  constexpr int NWV   = TH/64;
  constexpr int IW    = TILEB/1024/NWV;    // glds per wave per stage
  constexpr int NT    = K/64;
  constexpr int NF16  = N/16;
  constexpr int NYB   = N/BN;
  constexpr int WCN   = TH/128;            // waves in col dim
  constexpr int EPB   = LNEP ? 128*264*2 : (OBF ? 34816 : 0);
  constexpr int LDSB  = (2*TILEB > EPB) ? 2*TILEB : EPB;
  __shared__ char smem[LDSB];

  // fused degree-count role (GEMM1 only): first degBlocks blocks
  if ((int)blockIdx.x < degBlocks){
    int i = blockIdx.x*TH + threadIdx.x;
    if (i < dE0){ atomicAdd(&doc0[gs0[i]], 1); atomicAdd(&dic0[gd0[i]], 1); }
    if (i < dE1){ atomicAdd(&doc1[gs1[i]], 1); atomicAdd(&dic1[gd1[i]], 1); }
    return;
  }

  const int t = threadIdx.x;
  const int lane = t & 63;
  const int wv = t >> 6;
  const int wr = wv / WCN, wc = wv % WCN;

  int b;
  {
    int nb = gridDim.x - degBlocks, h = blockIdx.x - degBlocks;
    if (nb >= 8){
      int q = nb >> 3, r = nb & 7, k = h & 7, pos = h >> 3;
      b = (k < r ? k*(q+1) : r*(q+1) + (k-r)*q) + pos;
    } else b = h;
  }
  const int by = b % NYB;
  const int r0 = (b / NYB) * 128;
  const int c0 = by * BN;
  const int m15 = lane & 15, kg = lane >> 4;

  auto stage = [&](int buf, int ti){
    const int k0 = ti*64;
    char* bb = smem + buf*TILEB;
    #pragma unroll
    for (int s = 0; s < IW; ++s){
      int i16 = (wv*IW + s)*64 + lane;
      int row = i16 / SLOTS;
      int tt  = i16 & SMSK;
      int tsrc = tt ^ (row & SMSK);
      int grc = min(r0 + row, M-1);
      const char* g = (const char*)Av + ((size_t)grc*K + k0)*ESZ + tsrc*16;
      gl_lds16(g, bb + (wv*IW + s)*1024);
    }
  };

  f32x4 acc[4][4] = {};

  stage(0, 0);

  for (int ti = 0; ti < NT; ++ti){
    s16x8 bfr[2][4];
    #pragma unroll
    for (int kh = 0; kh < 2; ++kh)
      #pragma unroll
      for (int j = 0; j < 4; ++j)
        bfr[kh][j] = *(const s16x8*)(BPK +
          (((size_t)(2*ti+kh)*NF16 + (c0>>4) + wc*4 + j)*64 + lane)*8);
    __builtin_amdgcn_sched_barrier(0);

    if (ti + 1 < NT) stage((ti+1)&1, ti+1);
    __builtin_amdgcn_sched_barrier(0);

    // wait for stage(ti): outstanding afterwards = 8 bfr + IW stage(ti+1)
    if (ti + 1 < NT){
      constexpr int VW = 8 + IW;
      if constexpr (VW == 10) asm volatile("s_waitcnt vmcnt(10)");
      else if constexpr (VW == 12) asm volatile("s_waitcnt vmcnt(12)");
      else if constexpr (VW == 16) asm volatile("s_waitcnt vmcnt(16)");
      else asm volatile("s_waitcnt vmcnt(0)");
    } else {
      asm volatile("s_waitcnt vmcnt(8)");
    }
    __builtin_amdgcn_s_barrier();
    __builtin_amdgcn_sched_barrier(0);

    const char* bb = smem + (ti&1)*TILEB;
    s16x8 afr[2][4];
    #pragma unroll
    for (int kh = 0; kh < 2; ++kh){
      #pragma unroll
      for (int i = 0; i < 4; ++i){
        int row_l = wr*64 + i*16 + m15;
        if (ABF){
          int s = kh*4 + kg;
          int sw = s ^ (row_l & SMSK);
          afr[kh][i] = *(const s16x8*)(bb + row_l*ROWB + sw*16);
        } else {
          int s0 = kh*8 + kg*2;
          int sw0 = s0 ^ (row_l & SMSK);
          int sw1 = (s0+1) ^ (row_l & SMSK);
          float4 lo = *(const float4*)(bb + row_l*ROWB + sw0*16);
          float4 hi = *(const float4*)(bb + row_l*ROWB + sw1*16);
          s16x8 v;
          v[0]=(short)f2b(lo.x); v[1]=(short)f2b(lo.y); v[2]=(short)f2b(lo.z); v[3]=(short)f2b(lo.w);
          v[4]=(short)f2b(hi.x); v[5]=(short)f2b(hi.y); v[6]=(short)f2b(hi.z); v[7]=(short)f2b(hi.w);
          afr[kh][i] = v;
        }
      }
    }

    #pragma unroll
    for (int kh = 0; kh < 2; ++kh)
      #pragma unroll
      for (int i = 0; i < 4; ++i)
        #pragma unroll
        for (int j = 0; j < 4; ++j)
          acc[i][j] = __builtin_amdgcn_mfma_f32_16x16x32_bf16(afr[kh][i], bfr[kh][j], acc[i][j], 0, 0, 0);

    __builtin_amdgcn_sched_barrier(0);
    __builtin_amdgcn_s_barrier();
  }

  __syncthreads();

  if constexpr (LNEP){
    // conv1+LN: repack full 256-col rows into LDS, LN per row, write bf16
    u16* cs = (u16*)smem;
    #pragma unroll
    for (int j = 0; j < 4; ++j){
      int colL = wc*64 + j*16 + m15;
      float bv = bias[colL];
      #pragma unroll
      for (int i = 0; i < 4; ++i){
        int rl = wr*64 + i*16 + kg*4;
        #pragma unroll
        for (int q = 0; q < 4; ++q){
          float v = acc[i][j][q] + bv;
          if (RELU) v = fmaxf(v, 0.f);
          cs[(rl+q)*264 + colL] = f2b(v);
        }
      }
    }
    __syncthreads();
    float4 gv = ((const float4*)lng)[lane];
    float4 bvv = ((const float4*)lnb)[lane];
    constexpr int RPW = 128/NWV;
    #pragma unroll 4
    for (int rr = 0; rr < RPW; ++rr){
      int row = wv*RPW + rr;
      ushort4 u = *(const ushort4*)&cs[row*264 + lane*4];
      float x0=b2f(u.x), x1=b2f(u.y), x2=b2f(u.z), x3=b2f(u.w);
      float s = x0+x1+x2+x3;
      #pragma unroll
      for (int d=1; d<64; d<<=1) s += __shfl_xor(s, d);
      float mu = s * (1.f/256.f);
      float e0=x0-mu, e1=x1-mu, e2=x2-mu, e3=x3-mu;
      float vv = e0*e0 + e1*e1 + e2*e2 + e3*e3;
      #pragma unroll
      for (int d=1; d<64; d<<=1) vv += __shfl_xor(vv, d);
      float inv = rsqrtf(vv*(1.f/256.f) + 1e-5f);
      int gr = r0 + row;
      if (gr < M){
        ushort4 o;
        o.x = f2b(e0*inv*gv.x + bvv.x);
        o.y = f2b(e1*inv*gv.y + bvv.y);
        o.z = f2b(e2*inv*gv.z + bvv.z);
        o.w = f2b(e3*inv*gv.w + bvv.w);
        *(ushort4*)((u16*)Cv + (size_t)gr*256 + lane*4) = o;
      }
    }
  } else if constexpr (OBF){
    u16* cs = (u16*)smem;
    #pragma unroll
    for (int j = 0; j < 4; ++j){
      int colg = c0 + wc*64 + j*16 + m15;
      float bv = bias[colg];
      #pragma unroll
      for (int i = 0; i < 4; ++i){
        int rl = wr*64 + i*16 + kg*4;
        #pragma unroll
        for (int q = 0; q < 4; ++q){
          float v = acc[i][j][q] + bv;
          if (RELU) v = fmaxf(v, 0.f);
          cs[(rl+q)*136 + wc*64 + j*16 + m15] = f2b(v);
        }
      }
    }
    __syncthreads();
    int rr = t >> 1, hh = t & 1;
    int go = r0 + rr;
    if (go < M){
      u16* dst = (u16*)Cv + (size_t)go*N + c0 + hh*64;
      const u16* sp = &cs[rr*136 + hh*64];
      #pragma unroll
      for (int c = 0; c < 8; ++c) *(s16x8*)(dst + c*8) = *(const s16x8*)(sp + c*8);
    }
  } else {
    #pragma unroll
    for (int j = 0; j < 4; ++j){
      int colg = c0 + wc*64 + j*16 + m15;
      float bv = bias[colg];
      #pragma unroll
      for (int i = 0; i < 4; ++i){
        int rbase = r0 + wr*64 + i*16 + kg*4;
        #pragma unroll
        for (int q = 0; q < 4; ++q){
          int row = rbase + q;
          if (row < M){
            float v = acc[i][j][q] + bv;
            if (RELU) v = fmaxf(v, 0.f);
            ((float*)Cv)[(size_t)row*N + colg] = v;
          }
        }
      }
    }
  }
}

// ---- CSR pull aggregation: (src,scale) pairs, 4x-unrolled ----
__global__ __launch_bounds__(256) void agg_kernel(const u16* __restrict__ X,
    const int* __restrict__ off, const int2* __restrict__ lst,
    const float* __restrict__ ri, u16* __restrict__ out, int nd)
{
  int lane = threadIdx.x & 63, wv = threadIdx.x >> 6;
  int d = blockIdx.x*4 + wv;
  if (d >= nd) return;
  int e0 = off[d], e1 = off[d+1];
  float a0=0.f, a1=0.f, a2=0.f, a3=0.f;
  int e = e0;
  for (; e + 4 <= e1; e += 4){
    int2 p0 = lst[e], p1 = lst[e+1], p2 = lst[e+2], p3 = lst[e+3];
    float c0 = __int_as_float(p0.y), c1 = __int_as_float(p1.y);
    float c2 = __int_as_float(p2.y), c3 = __int_as_float(p3.y);
    ushort4 u0 = ((const ushort4*)X)[(size_t)p0.x*64 + lane];
    ushort4 u1 = ((const ushort4*)X)[(size_t)p1.x*64 + lane];
    ushort4 u2 = ((const ushort4*)X)[(size_t)p2.x*64 + lane];
    ushort4 u3 = ((const ushort4*)X)[(size_t)p3.x*64 + lane];
    a0 = fmaf(b2f(u0.x), c0, a0); a1 = fmaf(b2f(u0.y), c0, a1);
    a2 = fmaf(b2f(u0.z), c0, a2); a3 = fmaf(b2f(u0.w), c0, a3);
    a0 = fmaf(b2f(u1.x), c1, a0); a1 = fmaf(b2f(u1.y), c1, a1);
    a2 = fmaf(b2f(u1.z), c1, a2); a3 = fmaf(b2f(u1.w), c1, a3);
    a0 = fmaf(b2f(u2.x), c2, a0); a1 = fmaf(b2f(u2.y), c2, a1);
    a2 = fmaf(b2f(u2.z), c2, a2); a3 = fmaf(b2f(u2.w), c2, a3);
    a0 = fmaf(b2f(u3.x), c3, a0); a1 = fmaf(b2f(u3.y), c3, a1);
    a2 = fmaf(b2f(u3.z), c3, a2); a3 = fmaf(b2f(u3.w), c3, a3);
  }
  for (; e < e1; ++e){
    int2 pp = lst[e];
    float sc = __int_as_float(pp.y);
    ushort4 u = ((const ushort4*)X)[(size_t)pp.x*64 + lane];
    a0 = fmaf(b2f(u.x), sc, a0);
    a1 = fmaf(b2f(u.y), sc, a1);
    a2 = fmaf(b2f(u.z), sc, a2);
    a3 = fmaf(b2f(u.w), sc, a3);
  }
  float r = ri[d];
  ushort4 o;
  o.x = f2b(a0*r); o.y = f2b(a1*r); o.z = f2b(a2*r); o.w = f2b(a3*r);
  ((ushort4*)out)[(size_t)d*64 + lane] = o;
}

// ---- row L2-normalize, 128 cols ----
__global__ __launch_bounds__(256) void rownorm_kernel(const float* __restrict__ T,
    float* __restrict__ out, int n)
{
  int lane = threadIdx.x & 63, wv = threadIdx.x >> 6;
  int r = blockIdx.x*4 + wv;
  if (r >= n) return;
  float2 x = ((const float2*)T)[(size_t)r*64 + lane];
  float s = x.x*x.x + x.y*x.y;
  #pragma unroll
  for (int d=1; d<64; d<<=1) s += __shfl_xor(s, d);
  float nrm = sqrtf(s);
  float sc = 1.f / fmaxf(nrm, 1e-12f);
  float2 o; o.x = x.x*sc; o.y = x.y*sc;
  ((float2*)out)[(size_t)r*64 + lane] = o;
}

extern "C" void kernel_launch(void* const* d_in, const int* in_sizes, int n_in,
                              void* d_out, int out_size, void* d_ws, size_t ws_size,
                              hipStream_t stream)
{
  const float* feats = (const float*)d_in[0];
  const int*   b0s   = (const int*)d_in[1];
  const int*   b0d   = (const int*)d_in[2];
  const int*   b1s   = (const int*)d_in[3];
  const int*   b1d   = (const int*)d_in[4];
  const float* W1    = (const float*)d_in[5];
  const float* bias1 = (const float*)d_in[6];
  const float* Wc    = (const float*)d_in[7];
  const float* bc    = (const float*)d_in[8];
  const float* lng   = (const float*)d_in[9];
  const float* lnb   = (const float*)d_in[10];
  const float* Wo    = (const float*)d_in[11];
  const float* bo    = (const float*)d_in[12];
  const int E0 = in_sizes[1];
  const int E1 = in_sizes[3];
  (void)n_in; (void)out_size; (void)ws_size;

  char* p = (char*)d_ws;
  auto alloc = [&](size_t bytes)->void*{ void* q = (void*)p; p += (bytes + 255) & ~(size_t)255; return q; };
  u16*   g1   = (u16*)  alloc((size_t)NN0*HD*2);
  u16*   hb   = (u16*)  alloc((size_t)NN1*HD*2);
  u16*   ag2  = (u16*)  alloc((size_t)NN2*HD*2);
  float* c2   = (float*)alloc((size_t)NN2*OUT_D*4);
  u16*   W1P  = (u16*)  alloc((size_t)HD*IN_DIM*2);
  u16*   WcP  = (u16*)  alloc((size_t)HD*HD*2);
  u16*   WoP  = (u16*)  alloc((size_t)OUT_D*HD*2);
  char* cnt_begin = p;
  int* outc0 = (int*)alloc((size_t)NN0*4);
  int* inc0  = (int*)alloc((size_t)NN1*4);
  int* outc1 = (int*)alloc((size_t)NN1*4);
  int* inc1  = (int*)alloc((size_t)NN2*4);
  char* cnt_end = p;
  float* so0 = (float*)alloc((size_t)NN0*4);
  float* ri0 = (float*)alloc((size_t)NN1*4);
  float* so1 = (float*)alloc((size_t)NN1*4);
  float* ri1 = (float*)alloc((size_t)NN2*4);
  int* off0  = (int*)alloc((size_t)(NN1+1)*4);
  int* cur0  = (int*)alloc((size_t)NN1*4);
  int* off1  = (int*)alloc((size_t)(NN2+1)*4);
  int* cur1  = (int*)alloc((size_t)NN2*4);
  int2* lst0 = (int2*)alloc((size_t)800000*8);
  int2* lst1 = (int2*)alloc((size_t)160000*8);
  int* bsum  = (int*)alloc((size_t)(CH0+CH1)*4);

  // K1: zero counters + pack weights
  {
    int nbytes = (int)(cnt_end - cnt_begin);
    int n16 = nbytes >> 4;
    int nzb = (n16 + 255)/256;
    wpz_kernel<<<nzb + 112, 256, 0, stream>>>((int4*)cnt_begin, n16, nzb,
                                              W1, W1P, Wc, WcP, Wo, WoP);
  }

  // K2: GEMM1 + fused deg-count (deg blocks first; they ride idle wave slots)
  {
    int Emax = E0 > E1 ? E0 : E1;
    int degBlocks = (Emax + 255)/256;
    int nblk = ((NN0+127)/128) * (HD/128);
    gemm_glds<IN_DIM, HD, 128, 256, false, false, true, false>
      <<<degBlocks + nblk, 256, 0, stream>>>(feats, W1P, bias1, g1, NN0,
        nullptr, nullptr, b0s, b0d, E0, b1s, b1d, E1,
        outc0, inc0, outc1, inc1, degBlocks);
  }

  // K3: scan partials + rsqrt scales (both depend only on deg)
  scan_scale<<<CH0+CH1 + (NN0+1023)/1024, 1024, 0, stream>>>(
      inc0, off0, inc1, off1, bsum,
      outc0, so0, inc0, ri0, outc1, so1, inc1, ri1);

  // K4: add chunk bases (inlined bsum scan)
  scan_add<<<CH0+CH1, 1024, 0, stream>>>(off0, cur0, off1, cur1, bsum);

  // K5: CSR fill
  {
    int Emax = E0 > E1 ? E0 : E1;
    fill2_kernel<<<(Emax+255)/256, 256, 0, stream>>>(b0s, b0d, E0, cur0, lst0, so0,
                                                     b1s, b1d, E1, cur1, lst1, so1);
  }

  // K6: agg1 -> hb
  agg_kernel<<<(NN1+3)/4, 256, 0, stream>>>(g1, off0, lst0, ri0, hb, NN1);

  // K7: conv1 = relu(agg1 @ Wc + bc) with fused LayerNorm -> g1
  {
    int nblk = (NN1+127)/128;
    gemm_glds<HD, HD, 256, 512, true, true, false, true>
      <<<nblk, 512, 0, stream>>>(hb, WcP, bc, g1, NN1,
        lng, lnb, nullptr, nullptr, 0, nullptr, nullptr, 0,
        nullptr, nullptr, nullptr, nullptr, 0);
  }

  // K8: agg2 -> ag2
  agg_kernel<<<(NN2+3)/4, 256, 0, stream>>>(g1, off1, lst1, ri1, ag2, NN2);

  // K9: conv2 = agg2 @ Wo + bo -> c2 (f32)
  {
    int nblk = (NN2+127)/128;
    gemm_glds<HD, OUT_D, 128, 256, true, false, false, false>
      <<<nblk, 256, 0, stream>>>(ag2, WoP, bo, c2, NN2,
        nullptr, nullptr, nullptr, nullptr, 0, nullptr, nullptr, 0,
        nullptr, nullptr, nullptr, nullptr, 0);
  }

  // K10: row L2 normalize -> d_out
  rownorm_kernel<<<(NN2+3)/4, 256, 0, stream>>>(c2, (float*)d_out, NN2);
}

// Round 10
// 410.398 us; speedup vs baseline: 1.1713x; 1.0073x over previous
//
#include <hip/hip_runtime.h>
#include <hip/hip_bf16.h>

#define NN0 200000
#define NN1 50000
#define NN2 10000
#define IN_DIM 512
#define HD 256
#define OUT_D 128
#define CH0 ((NN1+1023)/1024)   // 49 scan chunks, graph0
#define CH1 ((NN2+1023)/1024)   // 10 scan chunks, graph1

typedef unsigned short u16;
typedef unsigned int u32;
typedef __attribute__((ext_vector_type(8))) short s16x8;
typedef __attribute__((ext_vector_type(4))) float f32x4;

__device__ __forceinline__ float b2f(u16 u){ return __uint_as_float(((u32)u)<<16); }
__device__ __forceinline__ u16 f2b(float f){
  u32 x = __float_as_uint(f);
  u32 r = x + 0x7fffu + ((x>>16)&1u);
  return (u16)(r>>16);
}

__device__ __forceinline__ void gl_lds16(const void* g, void* l){
  __builtin_amdgcn_global_load_lds((const __attribute__((address_space(1))) u32*)g,
                                   (__attribute__((address_space(3))) u32*)l, 16, 0, 0);
}

// ---- fused: zero counter region + pack weights ----
__device__ __forceinline__ void pack_one(const float* __restrict__ W, u16* __restrict__ out,
                                         int K, int N, int c){
  int lane = c & 63;
  int f = (c >> 6) % (N>>4);
  int s = (c >> 6) / (N>>4);
  int col = f*16 + (lane & 15);
  int k0 = s*32 + (lane >> 4)*8;
  u16* o = out + (size_t)c*8;
  #pragma unroll
  for (int e = 0; e < 8; ++e) o[e] = f2b(W[(size_t)(k0+e)*N + col]);
}

__global__ void wpz_kernel(int4* __restrict__ zp, int n16, int nzb,
                           const float* W1, u16* P1, const float* Wc, u16* Pc,
                           const float* Wo, u16* Po){
  int b = blockIdx.x;
  if (b < nzb){
    int i = b*256 + threadIdx.x;
    if (i < n16) zp[i] = make_int4(0,0,0,0);
  } else {
    int c = (b - nzb)*256 + threadIdx.x;
    if (c < 16384)      pack_one(W1, P1, IN_DIM, HD, c);
    else if (c < 24576) pack_one(Wc, Pc, HD, HD, c - 16384);
    else if (c < 28672) pack_one(Wo, Po, HD, OUT_D, c - 24576);
  }
}

// ---- degree counting, separate kernel (R9 fusion into GEMM1 thrashed L2: 248us vs 140+25) ----
__global__ void prep_deg(const int* __restrict__ s0, const int* __restrict__ d0, int E0,
                         const int* __restrict__ s1, const int* __restrict__ d1, int E1,
                         int* __restrict__ outc0, int* __restrict__ inc0,
                         int* __restrict__ outc1, int* __restrict__ inc1){
  int i = blockIdx.x*blockDim.x + threadIdx.x;
  if (i < E0){ atomicAdd(&outc0[s0[i]], 1); atomicAdd(&inc0[d0[i]], 1); }
  if (i < E1){ atomicAdd(&outc1[s1[i]], 1); atomicAdd(&inc1[d1[i]], 1); }
}

// ---- fused scan_part (blocks < CH0+CH1) + rsqrt scales (rest) ----
__global__ __launch_bounds__(1024) void scan_scale(
    const int* __restrict__ c0, int* __restrict__ o0,
    const int* __restrict__ c1, int* __restrict__ o1, int* __restrict__ bsum,
    const int* __restrict__ outc0, float* __restrict__ so0,
    const int* __restrict__ inc0,  float* __restrict__ ri0,
    const int* __restrict__ outc1, float* __restrict__ so1,
    const int* __restrict__ inc1,  float* __restrict__ ri1)
{
  int b = blockIdx.x;
  if (b >= CH0+CH1){
    int i = (b - CH0 - CH1)*1024 + threadIdx.x;
    if (i < NN0) so0[i] = rsqrtf((float)(outc0[i] > 1 ? outc0[i] : 1));
    if (i < NN1){
      ri0[i] = rsqrtf((float)(inc0[i]  > 1 ? inc0[i]  : 1));
      so1[i] = rsqrtf((float)(outc1[i] > 1 ? outc1[i] : 1));
    }
    if (i < NN2) ri1[i] = rsqrtf((float)(inc1[i] > 1 ? inc1[i] : 1));
    return;
  }
  __shared__ int wsum[16];
  const int* cnt; int* off; int n, base, slot;
  if (b < CH0){ cnt = c0; off = o0; n = NN1; base = b*1024; slot = b; }
  else        { int bb = b - CH0; cnt = c1; off = o1; n = NN2; base = bb*1024; slot = CH0 + bb; }
  int tid = threadIdx.x, lane = tid & 63, wv = tid >> 6;
  int i = base + tid;
  int v = (i < n) ? cnt[i] : 0;
  int x = v;
  #pragma unroll
  for (int d = 1; d < 64; d <<= 1){
    int y = __shfl_up(x, d);
    if (lane >= d) x += y;
  }
  if (lane == 63) wsum[wv] = x;
  __syncthreads();
  if (wv == 0){
    int s = (lane < 16) ? wsum[lane] : 0;
    #pragma unroll
    for (int d = 1; d < 16; d <<= 1){
      int y = __shfl_up(s, d);
      if (lane >= d) s += y;
    }
    if (lane < 16) wsum[lane] = s;
  }
  __syncthreads();
  int wbase = wv ? wsum[wv-1] : 0;
  if (i < n) off[i] = wbase + x - v;
  if (tid == 0) bsum[slot] = wsum[15];
}

// ---- scan_add with inlined chunk-base scan ----
__global__ __launch_bounds__(1024) void scan_add(int* __restrict__ o0, int* __restrict__ u0,
                                                 int* __restrict__ o1, int* __restrict__ u1,
                                                 const int* __restrict__ bsum){
  __shared__ int cbs;
  int b = blockIdx.x;
  int tid = threadIdx.x, lane = tid & 63, wv = tid >> 6;
  if (wv == 0){
    int v0 = (lane < CH0) ? bsum[lane] : 0;
    int x0 = v0;
    #pragma unroll
    for (int d = 1; d < 64; d <<= 1){ int y = __shfl_up(x0, d); if (lane >= d) x0 += y; }
    int v1 = (lane < CH1) ? bsum[CH0 + lane] : 0;
    int x1 = v1;
    #pragma unroll
    for (int d = 1; d < 64; d <<= 1){ int y = __shfl_up(x1, d); if (lane >= d) x1 += y; }
    int base = (b < CH0) ? __shfl(x0 - v0, b) : __shfl(x1 - v1, b - CH0);
    if (lane == 0) cbs = base;
    if (b == 0){
      if (lane == CH0-1) o0[NN1] = x0;
      if (lane == CH1-1) o1[NN2] = x1;
    }
  }
  __syncthreads();
  int base = cbs;
  int* off; int* cur; int n, i0;
  if (b < CH0){ off = o0; cur = u0; n = NN1; i0 = b*1024; }
  else        { off = o1; cur = u1; n = NN2; i0 = (b-CH0)*1024; }
  int i = i0 + tid;
  if (i < n){
    int t = off[i] + base;
    off[i] = t; cur[i] = t;
  }
}

// ---- fused CSR fill (src, out-scale) ----
__global__ void fill2_kernel(const int* __restrict__ s0, const int* __restrict__ d0, int E0,
                             int* __restrict__ cur0, int2* __restrict__ l0, const float* __restrict__ so0,
                             const int* __restrict__ s1, const int* __restrict__ d1, int E1,
                             int* __restrict__ cur1, int2* __restrict__ l1, const float* __restrict__ so1){
  int i = blockIdx.x*blockDim.x + threadIdx.x;
  if (i < E0){
    int s = s0[i];
    int p = atomicAdd(&cur0[d0[i]], 1);
    l0[p] = make_int2(s, __float_as_int(so0[s]));
  }
  if (i < E1){
    int s = s1[i];
    int p = atomicAdd(&cur1[d1[i]], 1);
    l1[p] = make_int2(s, __float_as_int(so1[s]));
  }
}

// ---- MFMA GEMM, glds staging, counted-vmcnt pipeline; optional fused LN epilogue ----
// TH threads (256: 4 waves 2x2; 512: 8 waves 2x4); per-wave output always 64x64.
template<int K, int N, int BN, int TH, bool ABF, bool RELU, bool OBF, bool LNEP>
__global__ __launch_bounds__(TH) void gemm_glds(const void* __restrict__ Av,
    const u16* __restrict__ BPK, const float* __restrict__ bias,
    void* __restrict__ Cv, int M,
    const float* __restrict__ lng, const float* __restrict__ lnb)
{
  constexpr int ESZ   = ABF ? 2 : 4;
  constexpr int SLOTS = (64*ESZ)/16;
  constexpr int SMSK  = SLOTS - 1;
  constexpr int ROWB  = 64*ESZ;
  constexpr int TILEB = 128*64*ESZ;
  constexpr int NWV   = TH/64;
  constexpr int IW    = TILEB/1024/NWV;    // glds per wave per stage
  constexpr int NT    = K/64;
  constexpr int NF16  = N/16;
  constexpr int NYB   = N/BN;
  constexpr int WCN   = TH/128;            // waves in col dim
  constexpr int EPB   = LNEP ? 128*264*2 : (OBF ? 34816 : 0);
  constexpr int LDSB  = (2*TILEB > EPB) ? 2*TILEB : EPB;
  __shared__ char smem[LDSB];

  const int t = threadIdx.x;
  const int lane = t & 63;
  const int wv = t >> 6;
  const int wr = wv / WCN, wc = wv % WCN;

  int b;
  {
    int nb = gridDim.x, h = blockIdx.x;
    if (nb >= 8){
      int q = nb >> 3, r = nb & 7, k = h & 7, pos = h >> 3;
      b = (k < r ? k*(q+1) : r*(q+1) + (k-r)*q) + pos;
    } else b = h;
  }
  const int by = b % NYB;
  const int r0 = (b / NYB) * 128;
  const int c0 = by * BN;
  const int m15 = lane & 15, kg = lane >> 4;

  auto stage = [&](int buf, int ti){
    const int k0 = ti*64;
    char* bb = smem + buf*TILEB;
    #pragma unroll
    for (int s = 0; s < IW; ++s){
      int i16 = (wv*IW + s)*64 + lane;
      int row = i16 / SLOTS;
      int tt  = i16 & SMSK;
      int tsrc = tt ^ (row & SMSK);
      int grc = min(r0 + row, M-1);
      const char* g = (const char*)Av + ((size_t)grc*K + k0)*ESZ + tsrc*16;
      gl_lds16(g, bb + (wv*IW + s)*1024);
    }
  };

  f32x4 acc[4][4] = {};

  stage(0, 0);

  for (int ti = 0; ti < NT; ++ti){
    s16x8 bfr[2][4];
    #pragma unroll
    for (int kh = 0; kh < 2; ++kh)
      #pragma unroll
      for (int j = 0; j < 4; ++j)
        bfr[kh][j] = *(const s16x8*)(BPK +
          (((size_t)(2*ti+kh)*NF16 + (c0>>4) + wc*4 + j)*64 + lane)*8);
    __builtin_amdgcn_sched_barrier(0);

    if (ti + 1 < NT) stage((ti+1)&1, ti+1);
    __builtin_amdgcn_sched_barrier(0);

    // wait for stage(ti): outstanding afterwards = 8 bfr + IW stage(ti+1)
    if (ti + 1 < NT){
      constexpr int VW = 8 + IW;
      if constexpr (VW == 10) asm volatile("s_waitcnt vmcnt(10)");
      else if constexpr (VW == 12) asm volatile("s_waitcnt vmcnt(12)");
      else if constexpr (VW == 16) asm volatile("s_waitcnt vmcnt(16)");
      else asm volatile("s_waitcnt vmcnt(0)");
    } else {
      asm volatile("s_waitcnt vmcnt(8)");
    }
    __builtin_amdgcn_s_barrier();
    __builtin_amdgcn_sched_barrier(0);

    const char* bb = smem + (ti&1)*TILEB;
    s16x8 afr[2][4];
    #pragma unroll
    for (int kh = 0; kh < 2; ++kh){
      #pragma unroll
      for (int i = 0; i < 4; ++i){
        int row_l = wr*64 + i*16 + m15;
        if (ABF){
          int s = kh*4 + kg;
          int sw = s ^ (row_l & SMSK);
          afr[kh][i] = *(const s16x8*)(bb + row_l*ROWB + sw*16);
        } else {
          int s0 = kh*8 + kg*2;
          int sw0 = s0 ^ (row_l & SMSK);
          int sw1 = (s0+1) ^ (row_l & SMSK);
          float4 lo = *(const float4*)(bb + row_l*ROWB + sw0*16);
          float4 hi = *(const float4*)(bb + row_l*ROWB + sw1*16);
          s16x8 v;
          v[0]=(short)f2b(lo.x); v[1]=(short)f2b(lo.y); v[2]=(short)f2b(lo.z); v[3]=(short)f2b(lo.w);
          v[4]=(short)f2b(hi.x); v[5]=(short)f2b(hi.y); v[6]=(short)f2b(hi.z); v[7]=(short)f2b(hi.w);
          afr[kh][i] = v;
        }
      }
    }

    #pragma unroll
    for (int kh = 0; kh < 2; ++kh)
      #pragma unroll
      for (int i = 0; i < 4; ++i)
        #pragma unroll
        for (int j = 0; j < 4; ++j)
          acc[i][j] = __builtin_amdgcn_mfma_f32_16x16x32_bf16(afr[kh][i], bfr[kh][j], acc[i][j], 0, 0, 0);

    __builtin_amdgcn_sched_barrier(0);
    __builtin_amdgcn_s_barrier();
  }

  __syncthreads();

  if constexpr (LNEP){
    // conv1+LN: repack full 256-col rows into LDS, LN per row, write bf16
    u16* cs = (u16*)smem;
    #pragma unroll
    for (int j = 0; j < 4; ++j){
      int colL = wc*64 + j*16 + m15;
      float bv = bias[colL];
      #pragma unroll
      for (int i = 0; i < 4; ++i){
        int rl = wr*64 + i*16 + kg*4;
        #pragma unroll
        for (int q = 0; q < 4; ++q){
          float v = acc[i][j][q] + bv;
          if (RELU) v = fmaxf(v, 0.f);
          cs[(rl+q)*264 + colL] = f2b(v);
        }
      }
    }
    __syncthreads();
    float4 gv = ((const float4*)lng)[lane];
    float4 bvv = ((const float4*)lnb)[lane];
    constexpr int RPW = 128/NWV;
    #pragma unroll 4
    for (int rr = 0; rr < RPW; ++rr){
      int row = wv*RPW + rr;
      ushort4 u = *(const ushort4*)&cs[row*264 + lane*4];
      float x0=b2f(u.x), x1=b2f(u.y), x2=b2f(u.z), x3=b2f(u.w);
      float s = x0+x1+x2+x3;
      #pragma unroll
      for (int d=1; d<64; d<<=1) s += __shfl_xor(s, d);
      float mu = s * (1.f/256.f);
      float e0=x0-mu, e1=x1-mu, e2=x2-mu, e3=x3-mu;
      float vv = e0*e0 + e1*e1 + e2*e2 + e3*e3;
      #pragma unroll
      for (int d=1; d<64; d<<=1) vv += __shfl_xor(vv, d);
      float inv = rsqrtf(vv*(1.f/256.f) + 1e-5f);
      int gr = r0 + row;
      if (gr < M){
        ushort4 o;
        o.x = f2b(e0*inv*gv.x + bvv.x);
        o.y = f2b(e1*inv*gv.y + bvv.y);
        o.z = f2b(e2*inv*gv.z + bvv.z);
        o.w = f2b(e3*inv*gv.w + bvv.w);
        *(ushort4*)((u16*)Cv + (size_t)gr*256 + lane*4) = o;
      }
    }
  } else if constexpr (OBF){
    u16* cs = (u16*)smem;
    #pragma unroll
    for (int j = 0; j < 4; ++j){
      int colg = c0 + wc*64 + j*16 + m15;
      float bv = bias[colg];
      #pragma unroll
      for (int i = 0; i < 4; ++i){
        int rl = wr*64 + i*16 + kg*4;
        #pragma unroll
        for (int q = 0; q < 4; ++q){
          float v = acc[i][j][q] + bv;
          if (RELU) v = fmaxf(v, 0.f);
          cs[(rl+q)*136 + wc*64 + j*16 + m15] = f2b(v);
        }
      }
    }
    __syncthreads();
    int rr = t >> 1, hh = t & 1;
    int go = r0 + rr;
    if (go < M){
      u16* dst = (u16*)Cv + (size_t)go*N + c0 + hh*64;
      const u16* sp = &cs[rr*136 + hh*64];
      #pragma unroll
      for (int c = 0; c < 8; ++c) *(s16x8*)(dst + c*8) = *(const s16x8*)(sp + c*8);
    }
  } else {
    #pragma unroll
    for (int j = 0; j < 4; ++j){
      int colg = c0 + wc*64 + j*16 + m15;
      float bv = bias[colg];
      #pragma unroll
      for (int i = 0; i < 4; ++i){
        int rbase = r0 + wr*64 + i*16 + kg*4;
        #pragma unroll
        for (int q = 0; q < 4; ++q){
          int row = rbase + q;
          if (row < M){
            float v = acc[i][j][q] + bv;
            if (RELU) v = fmaxf(v, 0.f);
            ((float*)Cv)[(size_t)row*N + colg] = v;
          }
        }
      }
    }
  }
}

// ---- CSR pull aggregation: (src,scale) pairs, 4x-unrolled ----
__global__ __launch_bounds__(256) void agg_kernel(const u16* __restrict__ X,
    const int* __restrict__ off, const int2* __restrict__ lst,
    const float* __restrict__ ri, u16* __restrict__ out, int nd)
{
  int lane = threadIdx.x & 63, wv = threadIdx.x >> 6;
  int d = blockIdx.x*4 + wv;
  if (d >= nd) return;
  int e0 = off[d], e1 = off[d+1];
  float a0=0.f, a1=0.f, a2=0.f, a3=0.f;
  int e = e0;
  for (; e + 4 <= e1; e += 4){
    int2 p0 = lst[e], p1 = lst[e+1], p2 = lst[e+2], p3 = lst[e+3];
    float c0 = __int_as_float(p0.y), c1 = __int_as_float(p1.y);
    float c2 = __int_as_float(p2.y), c3 = __int_as_float(p3.y);
    ushort4 u0 = ((const ushort4*)X)[(size_t)p0.x*64 + lane];
    ushort4 u1 = ((const ushort4*)X)[(size_t)p1.x*64 + lane];
    ushort4 u2 = ((const ushort4*)X)[(size_t)p2.x*64 + lane];
    ushort4 u3 = ((const ushort4*)X)[(size_t)p3.x*64 + lane];
    a0 = fmaf(b2f(u0.x), c0, a0); a1 = fmaf(b2f(u0.y), c0, a1);
    a2 = fmaf(b2f(u0.z), c0, a2); a3 = fmaf(b2f(u0.w), c0, a3);
    a0 = fmaf(b2f(u1.x), c1, a0); a1 = fmaf(b2f(u1.y), c1, a1);
    a2 = fmaf(b2f(u1.z), c1, a2); a3 = fmaf(b2f(u1.w), c1, a3);
    a0 = fmaf(b2f(u2.x), c2, a0); a1 = fmaf(b2f(u2.y), c2, a1);
    a2 = fmaf(b2f(u2.z), c2, a2); a3 = fmaf(b2f(u2.w), c2, a3);
    a0 = fmaf(b2f(u3.x), c3, a0); a1 = fmaf(b2f(u3.y), c3, a1);
    a2 = fmaf(b2f(u3.z), c3, a2); a3 = fmaf(b2f(u3.w), c3, a3);
  }
  for (; e < e1; ++e){
    int2 pp = lst[e];
    float sc = __int_as_float(pp.y);
    ushort4 u = ((const ushort4*)X)[(size_t)pp.x*64 + lane];
    a0 = fmaf(b2f(u.x), sc, a0);
    a1 = fmaf(b2f(u.y), sc, a1);
    a2 = fmaf(b2f(u.z), sc, a2);
    a3 = fmaf(b2f(u.w), sc, a3);
  }
  float r = ri[d];
  ushort4 o;
  o.x = f2b(a0*r); o.y = f2b(a1*r); o.z = f2b(a2*r); o.w = f2b(a3*r);
  ((ushort4*)out)[(size_t)d*64 + lane] = o;
}

// ---- row L2-normalize, 128 cols ----
__global__ __launch_bounds__(256) void rownorm_kernel(const float* __restrict__ T,
    float* __restrict__ out, int n)
{
  int lane = threadIdx.x & 63, wv = threadIdx.x >> 6;
  int r = blockIdx.x*4 + wv;
  if (r >= n) return;
  float2 x = ((const float2*)T)[(size_t)r*64 + lane];
  float s = x.x*x.x + x.y*x.y;
  #pragma unroll
  for (int d=1; d<64; d<<=1) s += __shfl_xor(s, d);
  float nrm = sqrtf(s);
  float sc = 1.f / fmaxf(nrm, 1e-12f);
  float2 o; o.x = x.x*sc; o.y = x.y*sc;
  ((float2*)out)[(size_t)r*64 + lane] = o;
}

extern "C" void kernel_launch(void* const* d_in, const int* in_sizes, int n_in,
                              void* d_out, int out_size, void* d_ws, size_t ws_size,
                              hipStream_t stream)
{
  const float* feats = (const float*)d_in[0];
  const int*   b0s   = (const int*)d_in[1];
  const int*   b0d   = (const int*)d_in[2];
  const int*   b1s   = (const int*)d_in[3];
  const int*   b1d   = (const int*)d_in[4];
  const float* W1    = (const float*)d_in[5];
  const float* bias1 = (const float*)d_in[6];
  const float* Wc    = (const float*)d_in[7];
  const float* bc    = (const float*)d_in[8];
  const float* lng   = (const float*)d_in[9];
  const float* lnb   = (const float*)d_in[10];
  const float* Wo    = (const float*)d_in[11];
  const float* bo    = (const float*)d_in[12];
  const int E0 = in_sizes[1];
  const int E1 = in_sizes[3];
  (void)n_in; (void)out_size; (void)ws_size;

  char* p = (char*)d_ws;
  auto alloc = [&](size_t bytes)->void*{ void* q = (void*)p; p += (bytes + 255) & ~(size_t)255; return q; };
  u16*   g1   = (u16*)  alloc((size_t)NN0*HD*2);
  u16*   hb   = (u16*)  alloc((size_t)NN1*HD*2);
  u16*   ag2  = (u16*)  alloc((size_t)NN2*HD*2);
  float* c2   = (float*)alloc((size_t)NN2*OUT_D*4);
  u16*   W1P  = (u16*)  alloc((size_t)HD*IN_DIM*2);
  u16*   WcP  = (u16*)  alloc((size_t)HD*HD*2);
  u16*   WoP  = (u16*)  alloc((size_t)OUT_D*HD*2);
  char* cnt_begin = p;
  int* outc0 = (int*)alloc((size_t)NN0*4);
  int* inc0  = (int*)alloc((size_t)NN1*4);
  int* outc1 = (int*)alloc((size_t)NN1*4);
  int* inc1  = (int*)alloc((size_t)NN2*4);
  char* cnt_end = p;
  float* so0 = (float*)alloc((size_t)NN0*4);
  float* ri0 = (float*)alloc((size_t)NN1*4);
  float* so1 = (float*)alloc((size_t)NN1*4);
  float* ri1 = (float*)alloc((size_t)NN2*4);
  int* off0  = (int*)alloc((size_t)(NN1+1)*4);
  int* cur0  = (int*)alloc((size_t)NN1*4);
  int* off1  = (int*)alloc((size_t)(NN2+1)*4);
  int* cur1  = (int*)alloc((size_t)NN2*4);
  int2* lst0 = (int2*)alloc((size_t)800000*8);
  int2* lst1 = (int2*)alloc((size_t)160000*8);
  int* bsum  = (int*)alloc((size_t)(CH0+CH1)*4);

  // K1: zero counters + pack weights
  {
    int nbytes = (int)(cnt_end - cnt_begin);
    int n16 = nbytes >> 4;
    int nzb = (n16 + 255)/256;
    wpz_kernel<<<nzb + 112, 256, 0, stream>>>((int4*)cnt_begin, n16, nzb,
                                              W1, W1P, Wc, WcP, Wo, WoP);
  }

  // K2: degree counting (kept separate: fusing into GEMM1 thrashed L2, R9)
  {
    int Emax = E0 > E1 ? E0 : E1;
    prep_deg<<<(Emax+255)/256, 256, 0, stream>>>(b0s, b0d, E0, b1s, b1d, E1,
                                                 outc0, inc0, outc1, inc1);
  }

  // K3: GEMM1  h = feats @ W1 + bias1 -> g1 (bf16)
  {
    int nblk = ((NN0+127)/128) * (HD/128);
    gemm_glds<IN_DIM, HD, 128, 256, false, false, true, false>
      <<<nblk, 256, 0, stream>>>(feats, W1P, bias1, g1, NN0, nullptr, nullptr);
  }

  // K4: scan partials + rsqrt scales
  scan_scale<<<CH0+CH1 + (NN0+1023)/1024, 1024, 0, stream>>>(
      inc0, off0, inc1, off1, bsum,
      outc0, so0, inc0, ri0, outc1, so1, inc1, ri1);

  // K5: add chunk bases
  scan_add<<<CH0+CH1, 1024, 0, stream>>>(off0, cur0, off1, cur1, bsum);

  // K6: CSR fill
  {
    int Emax = E0 > E1 ? E0 : E1;
    fill2_kernel<<<(Emax+255)/256, 256, 0, stream>>>(b0s, b0d, E0, cur0, lst0, so0,
                                                     b1s, b1d, E1, cur1, lst1, so1);
  }

  // K7: agg1 -> hb
  agg_kernel<<<(NN1+3)/4, 256, 0, stream>>>(g1, off0, lst0, ri0, hb, NN1);

  // K8: conv1 = relu(agg1 @ Wc + bc) with fused LayerNorm -> g1
  {
    int nblk = (NN1+127)/128;
    gemm_glds<HD, HD, 256, 512, true, true, false, true>
      <<<nblk, 512, 0, stream>>>(hb, WcP, bc, g1, NN1, lng, lnb);
  }

  // K9: agg2 -> ag2
  agg_kernel<<<(NN2+3)/4, 256, 0, stream>>>(g1, off1, lst1, ri1, ag2, NN2);

  // K10: conv2 = agg2 @ Wo + bo -> c2 (f32)
  {
    int nblk = (NN2+127)/128;
    gemm_glds<HD, OUT_D, 128, 256, true, false, false, false>
      <<<nblk, 256, 0, stream>>>(ag2, WoP, bo, c2, NN2, nullptr, nullptr);
  }

  // K11: row L2 normalize -> d_out
  rownorm_kernel<<<(NN2+3)/4, 256, 0, stream>>>(c2, (float*)d_out, NN2);
}